// Round 16
// baseline (313.248 us; speedup 1.0000x reference)
//
#include <hip/hip_runtime.h>
#include <hip/hip_bf16.h>
#include <stdint.h>

// ======================================================================
// EMSA fused pipeline. Device dtype (bf16 vs f32) detected at runtime.
// Algebra:
//  * S_i = Q_i K_i^T /8 once per input head (9.7 GF); head-mix tw applied
//    in-register; PV per head. All of QK->mix->softmax->dev->PV fused in
//    ONE kernel with S resident in LDS (68KB/block) — kills the 600MB
//    S/Dev HBM round-trip of the 3-kernel split.
//  * softmax row-sums are 1  =>  instance-norm mean = 1/256 exactly
//  * Dev = P - 1/256; var = mean(Dev^2); out = (Dev@V)*rsqrt(va+eps)
//  * tb cancels in softmax; 1/sqrt(dk) folded into WqT/bq;
//    instance-norm scale folded into per-batch pre-scaled Wo^T.
// R16: attn_lds replaces gemm_s+mix_softmax+gemm_pv. Previous fusion
//     failures were REGISTER-residency (R4/R8/R9: 64+ acc f32/lane);
//     LDS-residency keeps VGPR in the mix-kernel class. K/V fragments
//     read directly from global (L2-hot, 256KB/batch). mix math is
//     R14's exact verified code (R15 packed-math regression reverted).
// ======================================================================

typedef __bf16 bf16;
typedef __bf16 bf16x4 __attribute__((ext_vector_type(4)));
typedef __bf16 bf16x8 __attribute__((ext_vector_type(8)));
typedef float  f32x4  __attribute__((ext_vector_type(4)));

#define LDS_AS  __attribute__((address_space(3)))
#define GLOB_AS __attribute__((address_space(1)))

__device__ __forceinline__ void gload_lds16(const bf16* g, void* l) {
    __builtin_amdgcn_global_load_lds((const GLOB_AS void*)g, (LDS_AS void*)l, 16, 0, 0);
}

// ---------------- constants ----------------
#define NB   16
#define NQ   2304
#define DD   512
#define NKV  256

// workspace layout (bytes)
constexpr size_t OFF_WQT = 0;
constexpr size_t OFF_WKT = 512*512*2;
constexpr size_t OFF_WVT = 2*512*512*2;
constexpr size_t OFF_WOT = 3*512*512*2;
constexpr size_t OFF_X   = 4*512*512*2;
constexpr size_t OFF_KT  = OFF_X  + 4194304;
constexpr size_t OFF_VT  = OFF_KT + 4194304;
constexpr size_t OFF_SS  = OFF_VT + 4194304;
constexpr size_t OFF_SM  = OFF_SS + 512;
constexpr size_t OFF_TWF = OFF_SM + 40192;               // SM incl. srwT
constexpr size_t OFF_FLG = OFF_TWF + 256;
constexpr size_t OFF_QF  = OFF_FLG + 256;
constexpr size_t OFF_U   = OFF_QF + (size_t)NB*NQ*DD*2;
constexpr size_t OFF_WOTP = OFF_X;   // aliases X+KT (dead by scale_wot)

// small-region element offsets
#define SM_BQ   0
#define SM_BK   512
#define SM_BV   1024
#define SM_BO   1536
#define SM_SRW  2048
#define SM_SRB  10240
#define SM_LNG  10752
#define SM_LNB  11264
#define SM_TW   11776
#define SM_SRWT 11840   /* [tap][ch] transposed depthwise weights, 16x512 */

// ---------------- dtype detection ----------------
__global__ __launch_bounds__(64) void detect_dtype(const uint32_t* __restrict__ q,
                                                   int* __restrict__ flag)
{
    int t = threadIdx.x;
    int cnt = 0;
    #pragma unroll
    for (int i = 0; i < 8; i++) {
        uint32_t w = q[t*8 + i];
        int e = (w >> 7) & 0xFF;
        cnt += (e >= 100 && e <= 150) ? 1 : 0;
    }
    #pragma unroll
    for (int m = 1; m < 64; m <<= 1) cnt += __shfl_xor(cnt, m);
    if (t == 0) *flag = (cnt >= 384) ? 0 : 1;   // 0=bf16, 1=f32
}

// ---------------- input conversion (work only for f32 input) ----------------
__global__ __launch_bounds__(256) void convert_q(const void* __restrict__ in,
                                                 bf16* __restrict__ out,
                                                 const int* __restrict__ flag)
{
    if (*flag == 0) return;
    int idx = blockIdx.x * 256 + threadIdx.x;
    f32x4 a = ((const f32x4*)in)[(size_t)idx*2];
    f32x4 b = ((const f32x4*)in)[(size_t)idx*2 + 1];
    bf16x8 r;
    #pragma unroll
    for (int i = 0; i < 4; i++) { r[i] = (bf16)a[i]; r[i+4] = (bf16)b[i]; }
    ((bf16x8*)out)[idx] = r;
}

__global__ __launch_bounds__(256) void convert_small(
    const void* s0, const void* s1, const void* s2, const void* s3,
    const void* s4, const void* s5, const void* s6, const void* s7,
    const void* s8, bf16* __restrict__ dst, float* __restrict__ twf,
    const int* __restrict__ flag)
{
    const void* srcs[9] = {s0,s1,s2,s3,s4,s5,s6,s7,s8};
    const int sizes[9]  = {512,512,512,512,8192,512,512,512,64};
    const int offs[9]   = {SM_BQ,SM_BK,SM_BV,SM_BO,SM_SRW,SM_SRB,SM_LNG,SM_LNB,SM_TW};
    const float scl[9]  = {0.125f,1.f,1.f,1.f,1.f,1.f,1.f,1.f,1.f};
    int b = blockIdx.x;
    const void* s = srcs[b];
    int n = sizes[b], o = offs[b];
    float sc = scl[b];
    bool f32 = (*flag != 0);
    for (int i = threadIdx.x; i < n; i += 256) {
        float v = f32 ? ((const float*)s)[i] : (float)((const bf16*)s)[i];
        dst[o + i] = (bf16)(v * sc);
        if (b == 8) twf[i] = v;
        if (b == 4) {
            int tap = i & 15, ch = i >> 4;
            dst[SM_SRWT + tap*DD + ch] = (bf16)v;
        }
    }
}

// ---------------- weight transpose (512x512) ----------------
__global__ __launch_bounds__(256) void transpose512(
    const void* s0, const void* s1, const void* s2, const void* s3,
    bf16* __restrict__ d0, bf16* __restrict__ d1,
    bf16* __restrict__ d2, bf16* __restrict__ d3,
    const int* __restrict__ flag)
{
    __shared__ bf16 tile[32][33];
    bool f32 = (*flag != 0);
    int wsel = blockIdx.z;
    const void* src = wsel == 0 ? s0 : wsel == 1 ? s1 : wsel == 2 ? s2 : s3;
    bf16*       dst = wsel == 0 ? d0 : wsel == 1 ? d1 : wsel == 2 ? d2 : d3;
    float scl = (wsel == 0) ? 0.125f : 1.0f;
    int c0 = blockIdx.x * 32, n0 = blockIdx.y * 32;
    int tx = threadIdx.x, ty = threadIdx.y;
    #pragma unroll
    for (int i = 0; i < 4; i++) {
        size_t idx = (size_t)(c0 + ty + i*8) * 512 + n0 + tx;
        float v = f32 ? ((const float*)src)[idx] : (float)((const bf16*)src)[idx];
        tile[ty + i*8][tx] = (bf16)(v * scl);
    }
    __syncthreads();
    #pragma unroll
    for (int i = 0; i < 4; i++)
        dst[(size_t)(n0 + ty + i*8) * 512 + c0 + tx] = tile[tx][ty + i*8];
}

// ---------------- depthwise 4x4/s3 conv + LayerNorm (wave-per-output) ------------
__global__ __launch_bounds__(256) void sr_ln(
    const void* __restrict__ qraw, const bf16* __restrict__ qc,
    const bf16* __restrict__ sm, bf16* __restrict__ x,
    const int* __restrict__ flag)
{
    const bf16* q = (*flag) ? qc : (const bf16*)qraw;
    const int t = threadIdx.x;
    const int w = t >> 6, lane = t & 63;
    const int pos = blockIdx.x * 4 + w;        // b*256 + ok
    const int b = pos >> 8, ok = pos & 255;
    const int oh = ok >> 4, ow = ok & 15;
    const int c0 = lane * 8;

    float acc[8] = {};
    #pragma unroll
    for (int kh = 0; kh < 4; kh++) {
        int ih = oh*3 - 1 + kh;
        if (ih < 0) continue;
        #pragma unroll
        for (int kw = 0; kw < 4; kw++) {
            int iw = ow*3 - 1 + kw;
            if (iw < 0) continue;
            bf16x8 qv = *(const bf16x8*)(q + ((size_t)b*NQ + ih*48 + iw)*DD + c0);
            bf16x8 wv = *(const bf16x8*)(sm + SM_SRWT + (kh*4 + kw)*DD + c0);
            #pragma unroll
            for (int r = 0; r < 8; r++) acc[r] += (float)qv[r] * (float)wv[r];
        }
    }
    bf16x8 sb = *(const bf16x8*)(sm + SM_SRB + c0);
    #pragma unroll
    for (int r = 0; r < 8; r++) acc[r] += (float)sb[r];

    float s = 0.f, s2 = 0.f;
    #pragma unroll
    for (int r = 0; r < 8; r++) { s += acc[r]; s2 += acc[r]*acc[r]; }
    #pragma unroll
    for (int m = 1; m < 64; m <<= 1) { s += __shfl_xor(s, m); s2 += __shfl_xor(s2, m); }
    float mu  = s * (1.f/512.f);
    float var = s2 * (1.f/512.f) - mu*mu;
    float inv = rsqrtf(var + 1e-5f);

    bf16x8 gv = *(const bf16x8*)(sm + SM_LNG + c0);
    bf16x8 bv = *(const bf16x8*)(sm + SM_LNB + c0);
    bf16x8 outv;
    #pragma unroll
    for (int r = 0; r < 8; r++)
        outv[r] = (bf16)((acc[r] - mu) * inv * (float)gv[r] + (float)bv[r]);
    *(bf16x8*)(x + (size_t)pos * DD + c0) = outv;
}

// ---------------- generic BT-GEMM: C(M,512) = A(M,512) @ Bt(512,512)^T + bias ----------
template <int MODE>
__global__ __launch_bounds__(256) void gemm_bt(
    const bf16* __restrict__ A, const bf16* __restrict__ Bt,
    const bf16* __restrict__ bias, bf16* __restrict__ C,
    const int* __restrict__ of32, const bf16* __restrict__ A2)
{
    constexpr int K = 512;
    __shared__ bf16 Al[128 * 64];
    __shared__ bf16 Bl[128 * 64];
    const int m0 = blockIdx.x * 128, n0 = blockIdx.y * 128;
    const int t = threadIdx.x;
    const int lane = t & 63, w = t >> 6;
    const int wr = w >> 1, wc = w & 1;
    const int gg = lane >> 4, li = lane & 15;
    const int fsw = (li & 7) << 4;
    bool f32o = false;
    if (MODE == 2) f32o = (*of32 != 0);

    const bf16* Ab = A;
    if (MODE == 4) Ab = (*of32) ? A2 : A;
    const bf16* Btb = Bt;
    if (MODE == 2) Btb = Bt + (size_t)(m0 / 2304) * (512 * 512);

    f32x4 acc[4][4] = {};

    for (int k0 = 0; k0 < K; k0 += 64) {
        #pragma unroll
        for (int p = 0; p < 4; p++) {
            int off = p*4096 + t*16;
            int row = off >> 7;
            int col = ((((off >> 4) & 7) ^ (row & 7)) << 3);
            gload_lds16(Ab + (size_t)(m0 + row)*K + k0 + col, (char*)Al + off);
        }
        #pragma unroll
        for (int p = 0; p < 4; p++) {
            int off = p*4096 + t*16;
            int row = off >> 7;
            int col = ((((off >> 4) & 7) ^ (row & 7)) << 3);
            gload_lds16(Btb + (size_t)(n0 + row)*K + k0 + col, (char*)Bl + off);
        }
        __syncthreads();
        #pragma unroll
        for (int kk = 0; kk < 2; kk++) {
            bf16x8 af[4], bfr[4];
            #pragma unroll
            for (int i = 0; i < 4; i++) {
                af[i]  = *(const bf16x8*)((char*)Al + (wr*64 + i*16 + li)*128 + ((kk*64 + gg*16) ^ fsw));
                bfr[i] = *(const bf16x8*)((char*)Bl + (wc*64 + i*16 + li)*128 + ((kk*64 + gg*16) ^ fsw));
            }
            __builtin_amdgcn_s_setprio(1);
            #pragma unroll
            for (int i = 0; i < 4; i++)
                #pragma unroll
                for (int j = 0; j < 4; j++)
                    acc[i][j] = __builtin_amdgcn_mfma_f32_16x16x32_bf16(af[i], bfr[j], acc[i][j], 0, 0, 0);
            __builtin_amdgcn_s_setprio(0);
        }
        __syncthreads();
    }

    #pragma unroll
    for (int i = 0; i < 4; i++) {
        #pragma unroll
        for (int j = 0; j < 4; j++) {
            int rbase = m0 + wr*64 + i*16 + gg*4;
            int c     = n0 + wc*64 + j*16 + li;
            float bv = (float)bias[c];
            #pragma unroll
            for (int jj = 0; jj < 4; jj++) {
                float val = acc[i][j][jj] + bv;
                int r = rbase + jj;
                if (MODE == 1) {
                    int bb = r >> 8, kk2 = r & 255;
                    int hh = c >> 6, dv = c & 63;
                    C[(((size_t)(bb*8 + hh))*64 + dv)*256 + kk2] = (bf16)val;
                } else if (MODE == 2) {
                    if (f32o) ((float*)C)[(size_t)r * 512 + c] = val;
                    else      C[(size_t)r * 512 + c] = (bf16)val;
                } else {
                    C[(size_t)r * 512 + c] = (bf16)val;
                }
            }
        }
    }
}

// ---------------- fused attention, S resident in LDS ----------------
// grid (144, 16) = (q-tile of 16 rows, batch). 512 threads = 8 waves.
// Phase 1 (QK): wave w computes S_w[16x256] = Q_w @ K_w^T (K=64), fragments
//   loaded DIRECTLY from global (L2-hot), results scattered to LDS (1 acc live).
// Phase 2 (mix): R14's verified mix/softmax/dev math, in-place on LDS;
//   wave w owns q-rows {2w, 2w+1}; lane covers k = lane*4..+4.
// Phase 3 (PV): wave w computes U_w[16x64] = Dev_w @ V_w^T, A-frags from LDS,
//   B-frags from global VT.
__global__ __launch_bounds__(512, 4) void attn_lds(
    const bf16* __restrict__ Qf, const bf16* __restrict__ Kt,
    const bf16* __restrict__ VT, const float* __restrict__ twf,
    bf16* __restrict__ U, float* __restrict__ ssq_g)
{
    __shared__ bf16 Sl[8][16][264];      // 67,584 B (stride 264 keeps rows 16B-aligned)
    __shared__ float rpar[8][8];

    const int t = threadIdx.x;
    const int lane = t & 63, w = t >> 6;
    const int gg = lane >> 4, li = lane & 15;
    const int b = blockIdx.y;
    const int q0 = blockIdx.x * 16;

    // ---- phase 1: QK ----
    {
        const bf16* Qb = Qf + ((size_t)(b*NQ + q0 + li))*DD + w*64 + gg*8;
        const bf16* Kb = Kt + ((size_t)(b*NKV + li))*DD + w*64 + gg*8;
        bf16x8 af0 = *(const bf16x8*)(Qb);
        bf16x8 af1 = *(const bf16x8*)(Qb + 32);
        #pragma unroll
        for (int nt = 0; nt < 16; nt++) {
            bf16x8 b0 = *(const bf16x8*)(Kb + (size_t)(nt*16)*DD);
            bf16x8 b1 = *(const bf16x8*)(Kb + (size_t)(nt*16)*DD + 32);
            f32x4 a = {};
            a = __builtin_amdgcn_mfma_f32_16x16x32_bf16(af0, b0, a, 0, 0, 0);
            a = __builtin_amdgcn_mfma_f32_16x16x32_bf16(af1, b1, a, 0, 0, 0);
            #pragma unroll
            for (int jj = 0; jj < 4; jj++)
                Sl[w][gg*4 + jj][nt*16 + li] = (bf16)a[jj];
        }
    }
    __syncthreads();

    // ---- phase 2: mix + softmax + dev + ssq (in place on Sl) ----
    float tw[8][8];
    #pragma unroll
    for (int o = 0; o < 8; o++)
        #pragma unroll
        for (int i = 0; i < 8; i++)
            tw[o][i] = twf[o*8 + i];     // uniform address -> scalar load

    float ssqL[8] = {};
    #pragma unroll
    for (int qi = 0; qi < 2; qi++) {
        const int q = w*2 + qi;
        float s[8][4];
        #pragma unroll
        for (int i = 0; i < 8; i++) {
            bf16x4 v = *(const bf16x4*)&Sl[i][q][lane*4];
            #pragma unroll
            for (int r = 0; r < 4; r++) s[i][r] = (float)v[r];
        }
        float e[8][4], inv[8];
        #pragma unroll
        for (int o = 0; o < 8; o++) {
            float sum = 0.f;
            #pragma unroll
            for (int r = 0; r < 4; r++) {
                float a = 0.f;
                #pragma unroll
                for (int i = 0; i < 8; i++) a += tw[o][i] * s[i][r];
                e[o][r] = __expf(a);
                sum += e[o][r];
            }
            #pragma unroll
            for (int m = 1; m < 64; m <<= 1) sum += __shfl_xor(sum, m);
            inv[o] = 1.0f / sum;
        }
        #pragma unroll
        for (int o = 0; o < 8; o++) {
            bf16x4 dv;
            #pragma unroll
            for (int r = 0; r < 4; r++) {
                float d = e[o][r] * inv[o] - (1.0f/256.0f);
                ssqL[o] += d * d;
                dv[r] = (bf16)d;
            }
            *(bf16x4*)&Sl[o][q][lane*4] = dv;
        }
    }
    #pragma unroll
    for (int o = 0; o < 8; o++) {
        float s = ssqL[o];
        #pragma unroll
        for (int m = 1; m < 64; m <<= 1) s += __shfl_xor(s, m);
        if (lane == 0) rpar[w][o] = s;
    }
    __syncthreads();
    if (t < 8) {
        float tot = 0.f;
        #pragma unroll
        for (int i = 0; i < 8; i++) tot += rpar[i][t];
        atomicAdd(&ssq_g[b*8 + t], tot);
    }

    // ---- phase 3: PV ----
    {
        const bf16* Vb = VT + ((size_t)(b*8 + w))*64*NKV + (size_t)li*NKV + gg*8;
        f32x4 u0 = {}, u1 = {}, u2 = {}, u3 = {};
        #pragma unroll
        for (int ks = 0; ks < 8; ks++) {
            bf16x8 af = *(const bf16x8*)&Sl[w][li][ks*32 + gg*8];
            bf16x8 b0 = *(const bf16x8*)(Vb + ks*32);
            u0 = __builtin_amdgcn_mfma_f32_16x16x32_bf16(af, b0, u0, 0, 0, 0);
            bf16x8 b1 = *(const bf16x8*)(Vb + (size_t)16*NKV + ks*32);
            u1 = __builtin_amdgcn_mfma_f32_16x16x32_bf16(af, b1, u1, 0, 0, 0);
            bf16x8 b2 = *(const bf16x8*)(Vb + (size_t)32*NKV + ks*32);
            u2 = __builtin_amdgcn_mfma_f32_16x16x32_bf16(af, b2, u2, 0, 0, 0);
            bf16x8 b3 = *(const bf16x8*)(Vb + (size_t)48*NKV + ks*32);
            u3 = __builtin_amdgcn_mfma_f32_16x16x32_bf16(af, b3, u3, 0, 0, 0);
        }
        #pragma unroll
        for (int jj = 0; jj < 4; jj++) {
            bf16* row = U + ((size_t)(b*NQ + q0 + gg*4 + jj))*DD + w*64 + li;
            row[0]  = (bf16)u0[jj];
            row[16] = (bf16)u1[jj];
            row[32] = (bf16)u2[jj];
            row[48] = (bf16)u3[jj];
        }
    }
}

// ---------------- per-batch scaled Wo^T ----------------
__global__ __launch_bounds__(256) void scale_wot(const bf16* __restrict__ WoT,
                                                 const float* __restrict__ ssq,
                                                 bf16* __restrict__ out)
{
    int idx = blockIdx.x * 256 + threadIdx.x;
    int c8 = idx & 63;
    int c  = (idx >> 6) & 511;
    int b  = idx >> 15;
    int h  = c8 >> 3;
    float va = ssq[b*8 + h] * (1.0f / ((float)NQ * (float)NKV));
    float s  = rsqrtf(va + 1e-5f);
    bf16x8 v = *(const bf16x8*)(WoT + ((size_t)c << 9) + c8*8);
    bf16x8 r;
    #pragma unroll
    for (int i = 0; i < 8; i++) r[i] = (bf16)((float)v[i] * s);
    *(bf16x8*)(out + ((size_t)idx << 3)) = r;
}

// ======================================================================
extern "C" void kernel_launch(void* const* d_in, const int* in_sizes, int n_in,
                              void* d_out, int out_size, void* d_ws, size_t ws_size,
                              hipStream_t stream)
{
    const void* queries = d_in[0];
    const void* Wq = d_in[1];  const void* bq = d_in[2];
    const void* Wk = d_in[3];  const void* bk = d_in[4];
    const void* Wv = d_in[5];  const void* bv = d_in[6];
    const void* Wo = d_in[7];  const void* bo = d_in[8];
    const void* srw = d_in[9]; const void* srb = d_in[10];
    const void* lng = d_in[11]; const void* lnb = d_in[12];
    const void* tw  = d_in[13];
    // d_in[14] = tb: cancels in softmax; unused.

    char* ws = (char*)d_ws;
    bf16* WqT = (bf16*)(ws + OFF_WQT);
    bf16* WkT = (bf16*)(ws + OFF_WKT);
    bf16* WvT = (bf16*)(ws + OFF_WVT);
    bf16* WoT = (bf16*)(ws + OFF_WOT);
    bf16* xb  = (bf16*)(ws + OFF_X);
    bf16* Kt  = (bf16*)(ws + OFF_KT);
    bf16* VTb = (bf16*)(ws + OFF_VT);
    bf16* Qf  = (bf16*)(ws + OFF_QF);
    bf16* Ub  = (bf16*)(ws + OFF_U);
    float* ss = (float*)(ws + OFF_SS);
    bf16* sm  = (bf16*)(ws + OFF_SM);
    float* twf = (float*)(ws + OFF_TWF);
    int* flag = (int*)(ws + OFF_FLG);
    bf16* WoTp = (bf16*)(ws + OFF_WOTP);
    bf16* Qc  = Ub;                        // converted queries (f32 path); dead before attn writes U

    detect_dtype<<<dim3(1), dim3(64), 0, stream>>>((const uint32_t*)queries, flag);
    hipMemsetAsync(ss, 0, 128 * sizeof(float), stream);

    convert_q<<<dim3(9216), dim3(256), 0, stream>>>(queries, Qc, flag);
    convert_small<<<dim3(9), dim3(256), 0, stream>>>(bq, bk, bv, bo, srw, srb, lng, lnb, tw, sm, twf, flag);
    transpose512<<<dim3(16, 16, 4), dim3(32, 8), 0, stream>>>(Wq, Wk, Wv, Wo, WqT, WkT, WvT, WoT, flag);

    sr_ln<<<dim3(NB * NKV / 4), dim3(256), 0, stream>>>(queries, Qc, sm, xb, flag);
    gemm_bt<0><<<dim3(32, 4), dim3(256), 0, stream>>>(xb, WkT, sm + SM_BK, Kt, nullptr, nullptr);
    gemm_bt<1><<<dim3(32, 4), dim3(256), 0, stream>>>(xb, WvT, sm + SM_BV, VTb, nullptr, nullptr);
    gemm_bt<4><<<dim3(288, 4), dim3(256), 0, stream>>>((const bf16*)queries, WqT, sm + SM_BQ, Qf, flag, Qc);

    attn_lds<<<dim3(144, 16), dim3(512), 0, stream>>>(Qf, Kt, VTb, twf, Ub, ss);

    scale_wot<<<dim3(2048), dim3(256), 0, stream>>>(WoT, ss, WoTp);
    gemm_bt<2><<<dim3(288, 4), dim3(256), 0, stream>>>(Ub, WoTp, sm + SM_BO, (bf16*)d_out, flag, nullptr);
}

// Round 17
// 307.344 us; speedup vs baseline: 1.0192x; 1.0192x over previous
//
#include <hip/hip_runtime.h>
#include <hip/hip_bf16.h>
#include <stdint.h>

// ======================================================================
// EMSA fused pipeline. Device dtype (bf16 vs f32) detected at runtime.
// Algebra:
//  * S_i = Q_i K_i^T /8 once per input head (9.7 GF); head-mix tw applied
//    in a streaming VALU kernel; PV is a clean batched GEMM.
//  * softmax row-sums are 1  =>  instance-norm mean = 1/256 exactly
//  * Dev = P - 1/256; var = mean(Dev^2); out = (Dev@V)*rsqrt(va+eps)
//  * tb cancels in softmax; 1/sqrt(dk) folded into WqT/bq;
//    instance-norm scale folded into per-batch pre-scaled Wo^T.
// R17: base = R14 (best green, 294.6us; R15 packed-math and R16 LDS-fusion
//     both regressed and are reverted). convert_q ELIMINATED: sr_ln reads
//     f32 input directly; Q-GEMM (MODE 4) converts f32->bf16 during
//     reg-staged A-tile LDS writes (same swizzled offsets as the verified
//     read path). Saves ~35us of convert traffic for ~12us extra fetch.
// ======================================================================

typedef __bf16 bf16;
typedef __bf16 bf16x4 __attribute__((ext_vector_type(4)));
typedef __bf16 bf16x8 __attribute__((ext_vector_type(8)));
typedef float  f32x4  __attribute__((ext_vector_type(4)));

#define LDS_AS  __attribute__((address_space(3)))
#define GLOB_AS __attribute__((address_space(1)))

__device__ __forceinline__ void gload_lds16(const bf16* g, void* l) {
    __builtin_amdgcn_global_load_lds((const GLOB_AS void*)g, (LDS_AS void*)l, 16, 0, 0);
}

// ---------------- constants ----------------
#define NB   16
#define NQ   2304
#define DD   512
#define NKV  256

// workspace layout (bytes)
constexpr size_t OFF_WQT = 0;
constexpr size_t OFF_WKT = 512*512*2;
constexpr size_t OFF_WVT = 2*512*512*2;
constexpr size_t OFF_WOT = 3*512*512*2;
constexpr size_t OFF_X   = 4*512*512*2;
constexpr size_t OFF_KT  = OFF_X  + 4194304;
constexpr size_t OFF_VT  = OFF_KT + 4194304;
constexpr size_t OFF_SS  = OFF_VT + 4194304;
constexpr size_t OFF_SM  = OFF_SS + 512;
constexpr size_t OFF_TWF = OFF_SM + 40192;               // SM incl. srwT
constexpr size_t OFF_FLG = OFF_TWF + 256;
constexpr size_t OFF_QF  = OFF_FLG + 256;
constexpr size_t OFF_U   = OFF_QF + (size_t)NB*NQ*DD*2;
constexpr size_t OFF_S   = OFF_U  + (size_t)NB*NQ*DD*2;   // S/Dev chunk buffer
constexpr size_t SPLANE  = (size_t)NQ*NKV*2;
constexpr size_t OFF_WOTP = OFF_X;   // aliases X+KT (dead by scale_wot)

// small-region element offsets
#define SM_BQ   0
#define SM_BK   512
#define SM_BV   1024
#define SM_BO   1536
#define SM_SRW  2048
#define SM_SRB  10240
#define SM_LNG  10752
#define SM_LNB  11264
#define SM_TW   11776
#define SM_SRWT 11840   /* [tap][ch] transposed depthwise weights, 16x512 */

// ---------------- dtype detection ----------------
__global__ __launch_bounds__(64) void detect_dtype(const uint32_t* __restrict__ q,
                                                   int* __restrict__ flag)
{
    int t = threadIdx.x;
    int cnt = 0;
    #pragma unroll
    for (int i = 0; i < 8; i++) {
        uint32_t w = q[t*8 + i];
        int e = (w >> 7) & 0xFF;
        cnt += (e >= 100 && e <= 150) ? 1 : 0;
    }
    #pragma unroll
    for (int m = 1; m < 64; m <<= 1) cnt += __shfl_xor(cnt, m);
    if (t == 0) *flag = (cnt >= 384) ? 0 : 1;   // 0=bf16, 1=f32
}

// ---------------- small-input conversion ----------------
__global__ __launch_bounds__(256) void convert_small(
    const void* s0, const void* s1, const void* s2, const void* s3,
    const void* s4, const void* s5, const void* s6, const void* s7,
    const void* s8, bf16* __restrict__ dst, float* __restrict__ twf,
    const int* __restrict__ flag)
{
    const void* srcs[9] = {s0,s1,s2,s3,s4,s5,s6,s7,s8};
    const int sizes[9]  = {512,512,512,512,8192,512,512,512,64};
    const int offs[9]   = {SM_BQ,SM_BK,SM_BV,SM_BO,SM_SRW,SM_SRB,SM_LNG,SM_LNB,SM_TW};
    const float scl[9]  = {0.125f,1.f,1.f,1.f,1.f,1.f,1.f,1.f,1.f};
    int b = blockIdx.x;
    const void* s = srcs[b];
    int n = sizes[b], o = offs[b];
    float sc = scl[b];
    bool f32 = (*flag != 0);
    for (int i = threadIdx.x; i < n; i += 256) {
        float v = f32 ? ((const float*)s)[i] : (float)((const bf16*)s)[i];
        dst[o + i] = (bf16)(v * sc);
        if (b == 8) twf[i] = v;
        if (b == 4) {
            // transposed copy: srw is [ch][tap] (i = ch*16 + tap)
            int tap = i & 15, ch = i >> 4;
            dst[SM_SRWT + tap*DD + ch] = (bf16)v;
        }
    }
}

// ---------------- weight transpose (512x512) ----------------
__global__ __launch_bounds__(256) void transpose512(
    const void* s0, const void* s1, const void* s2, const void* s3,
    bf16* __restrict__ d0, bf16* __restrict__ d1,
    bf16* __restrict__ d2, bf16* __restrict__ d3,
    const int* __restrict__ flag)
{
    __shared__ bf16 tile[32][33];
    bool f32 = (*flag != 0);
    int wsel = blockIdx.z;
    const void* src = wsel == 0 ? s0 : wsel == 1 ? s1 : wsel == 2 ? s2 : s3;
    bf16*       dst = wsel == 0 ? d0 : wsel == 1 ? d1 : wsel == 2 ? d2 : d3;
    float scl = (wsel == 0) ? 0.125f : 1.0f;
    int c0 = blockIdx.x * 32, n0 = blockIdx.y * 32;
    int tx = threadIdx.x, ty = threadIdx.y;
    #pragma unroll
    for (int i = 0; i < 4; i++) {
        size_t idx = (size_t)(c0 + ty + i*8) * 512 + n0 + tx;
        float v = f32 ? ((const float*)src)[idx] : (float)((const bf16*)src)[idx];
        tile[ty + i*8][tx] = (bf16)(v * scl);
    }
    __syncthreads();
    #pragma unroll
    for (int i = 0; i < 4; i++)
        dst[(size_t)(n0 + ty + i*8) * 512 + c0 + tx] = tile[tx][ty + i*8];
}

// ---------------- depthwise 4x4/s3 conv + LayerNorm (wave-per-output) ------------
// Reads the raw input directly in either dtype (no converted-copy needed).
__global__ __launch_bounds__(256) void sr_ln(
    const void* __restrict__ qraw, const bf16* __restrict__ sm,
    bf16* __restrict__ x, const int* __restrict__ flag)
{
    const bool f32 = (*flag != 0);
    const int t = threadIdx.x;
    const int w = t >> 6, lane = t & 63;
    const int pos = blockIdx.x * 4 + w;        // b*256 + ok
    const int b = pos >> 8, ok = pos & 255;
    const int oh = ok >> 4, ow = ok & 15;
    const int c0 = lane * 8;

    float acc[8] = {};
    #pragma unroll
    for (int kh = 0; kh < 4; kh++) {
        int ih = oh*3 - 1 + kh;
        if (ih < 0) continue;
        #pragma unroll
        for (int kw = 0; kw < 4; kw++) {
            int iw = ow*3 - 1 + kw;
            if (iw < 0) continue;
            size_t base = ((size_t)b*NQ + ih*48 + iw)*DD + c0;
            float qf[8];
            if (f32) {
                f32x4 a = *(const f32x4*)((const float*)qraw + base);
                f32x4 c = *(const f32x4*)((const float*)qraw + base + 4);
                #pragma unroll
                for (int r = 0; r < 4; r++) { qf[r] = a[r]; qf[r+4] = c[r]; }
            } else {
                bf16x8 qv = *(const bf16x8*)((const bf16*)qraw + base);
                #pragma unroll
                for (int r = 0; r < 8; r++) qf[r] = (float)qv[r];
            }
            bf16x8 wv = *(const bf16x8*)(sm + SM_SRWT + (kh*4 + kw)*DD + c0);
            #pragma unroll
            for (int r = 0; r < 8; r++) acc[r] += qf[r] * (float)wv[r];
        }
    }
    bf16x8 sb = *(const bf16x8*)(sm + SM_SRB + c0);
    #pragma unroll
    for (int r = 0; r < 8; r++) acc[r] += (float)sb[r];

    float s = 0.f, s2 = 0.f;
    #pragma unroll
    for (int r = 0; r < 8; r++) { s += acc[r]; s2 += acc[r]*acc[r]; }
    #pragma unroll
    for (int m = 1; m < 64; m <<= 1) { s += __shfl_xor(s, m); s2 += __shfl_xor(s2, m); }
    float mu  = s * (1.f/512.f);
    float var = s2 * (1.f/512.f) - mu*mu;
    float inv = rsqrtf(var + 1e-5f);

    bf16x8 gv = *(const bf16x8*)(sm + SM_LNG + c0);
    bf16x8 bv = *(const bf16x8*)(sm + SM_LNB + c0);
    bf16x8 outv;
    #pragma unroll
    for (int r = 0; r < 8; r++)
        outv[r] = (bf16)((acc[r] - mu) * inv * (float)gv[r] + (float)bv[r]);
    *(bf16x8*)(x + (size_t)pos * DD + c0) = outv;
}

// ---------------- generic BT-GEMM: C(M,512) = A(M,512) @ Bt(512,512)^T + bias ----------
// MODE 0: bf16 row-major store. MODE 1: V^T scatter store (b,h,dv,kk).
// MODE 2: output GEMM (per-batch pre-scaled WoT, dtype-branch store).
// MODE 4: Q-GEMM; A may be f32 (flag) -> reg-staged convert into swizzled LDS.
template <int MODE>
__global__ __launch_bounds__(256) void gemm_bt(
    const bf16* __restrict__ A, const bf16* __restrict__ Bt,
    const bf16* __restrict__ bias, bf16* __restrict__ C,
    const int* __restrict__ of32)
{
    constexpr int K = 512;
    __shared__ bf16 Al[128 * 64];
    __shared__ bf16 Bl[128 * 64];
    const int m0 = blockIdx.x * 128, n0 = blockIdx.y * 128;
    const int t = threadIdx.x;
    const int lane = t & 63, w = t >> 6;
    const int wr = w >> 1, wc = w & 1;
    const int gg = lane >> 4, li = lane & 15;
    const int fsw = (li & 7) << 4;
    bool f32io = false;
    if (MODE == 2 || MODE == 4) f32io = (*of32 != 0);

    const bf16* Btb = Bt;
    if (MODE == 2) Btb = Bt + (size_t)(m0 / 2304) * (512 * 512);

    f32x4 acc[4][4] = {};

    for (int k0 = 0; k0 < K; k0 += 64) {
        if (MODE == 4 && f32io) {
            // reg-staged f32 -> bf16 conversion into the swizzled A layout
            #pragma unroll
            for (int p = 0; p < 4; p++) {
                int off = p*4096 + t*16;
                int row = off >> 7;
                int col = ((((off >> 4) & 7) ^ (row & 7)) << 3);
                const float* src = (const float*)A + (size_t)(m0 + row)*K + k0 + col;
                f32x4 v0 = *(const f32x4*)src;
                f32x4 v1 = *(const f32x4*)(src + 4);
                bf16x8 r;
                #pragma unroll
                for (int i = 0; i < 4; i++) { r[i] = (bf16)v0[i]; r[i+4] = (bf16)v1[i]; }
                *(bf16x8*)((char*)Al + off) = r;
            }
        } else {
            #pragma unroll
            for (int p = 0; p < 4; p++) {
                int off = p*4096 + t*16;
                int row = off >> 7;
                int col = ((((off >> 4) & 7) ^ (row & 7)) << 3);
                gload_lds16(A + (size_t)(m0 + row)*K + k0 + col, (char*)Al + off);
            }
        }
        #pragma unroll
        for (int p = 0; p < 4; p++) {
            int off = p*4096 + t*16;
            int row = off >> 7;
            int col = ((((off >> 4) & 7) ^ (row & 7)) << 3);
            gload_lds16(Btb + (size_t)(n0 + row)*K + k0 + col, (char*)Bl + off);
        }
        __syncthreads();
        #pragma unroll
        for (int kk = 0; kk < 2; kk++) {
            bf16x8 af[4], bfr[4];
            #pragma unroll
            for (int i = 0; i < 4; i++) {
                af[i]  = *(const bf16x8*)((char*)Al + (wr*64 + i*16 + li)*128 + ((kk*64 + gg*16) ^ fsw));
                bfr[i] = *(const bf16x8*)((char*)Bl + (wc*64 + i*16 + li)*128 + ((kk*64 + gg*16) ^ fsw));
            }
            __builtin_amdgcn_s_setprio(1);
            #pragma unroll
            for (int i = 0; i < 4; i++)
                #pragma unroll
                for (int j = 0; j < 4; j++)
                    acc[i][j] = __builtin_amdgcn_mfma_f32_16x16x32_bf16(af[i], bfr[j], acc[i][j], 0, 0, 0);
            __builtin_amdgcn_s_setprio(0);
        }
        __syncthreads();
    }

    #pragma unroll
    for (int i = 0; i < 4; i++) {
        #pragma unroll
        for (int j = 0; j < 4; j++) {
            int rbase = m0 + wr*64 + i*16 + gg*4;
            int c     = n0 + wc*64 + j*16 + li;
            float bv = (float)bias[c];
            #pragma unroll
            for (int jj = 0; jj < 4; jj++) {
                float val = acc[i][j][jj] + bv;
                int r = rbase + jj;
                if (MODE == 1) {
                    int bb = r >> 8, kk2 = r & 255;
                    int hh = c >> 6, dv = c & 63;
                    C[(((size_t)(bb*8 + hh))*64 + dv)*256 + kk2] = (bf16)val;
                } else if (MODE == 2) {
                    if (f32io) ((float*)C)[(size_t)r * 512 + c] = val;
                    else       C[(size_t)r * 512 + c] = (bf16)val;
                } else {
                    C[(size_t)r * 512 + c] = (bf16)val;
                }
            }
        }
    }
}

// ---------------- S-GEMM: S[plane] = Q_i @ K_i^T  (M=2304,N=256,K=64) ----------------
__global__ __launch_bounds__(256) void gemm_s(
    const bf16* __restrict__ Qf, const bf16* __restrict__ Kt, bf16* __restrict__ S,
    int b0)
{
    __shared__ bf16 Al[128 * 64];
    __shared__ bf16 Bl[128 * 64];
    const int m0 = blockIdx.x * 128, n0 = blockIdx.y * 128;
    const int bo = blockIdx.z;
    const int b = b0 + (bo >> 3), ih = bo & 7;
    const int t = threadIdx.x;
    const int lane = t & 63, w = t >> 6;
    const int wr = w >> 1, wc = w & 1;
    const int gg = lane >> 4, li = lane & 15;
    const int fsw = (li & 7) << 4;

    #pragma unroll
    for (int p = 0; p < 4; p++) {
        int off = p*4096 + t*16;
        int row = off >> 7;
        int col = ((((off >> 4) & 7) ^ (row & 7)) << 3);
        gload_lds16(Qf + ((size_t)(b*NQ + m0 + row))*DD + ih*64 + col, (char*)Al + off);
    }
    #pragma unroll
    for (int p = 0; p < 4; p++) {
        int off = p*4096 + t*16;
        int row = off >> 7;
        int col = ((((off >> 4) & 7) ^ (row & 7)) << 3);
        gload_lds16(Kt + ((size_t)(b*NKV + n0 + row))*DD + ih*64 + col, (char*)Bl + off);
    }
    __syncthreads();

    f32x4 acc[4][4] = {};
    #pragma unroll
    for (int kk = 0; kk < 2; kk++) {
        bf16x8 af[4], bfr[4];
        #pragma unroll
        for (int i = 0; i < 4; i++) {
            af[i]  = *(const bf16x8*)((char*)Al + (wr*64 + i*16 + li)*128 + ((kk*64 + gg*16) ^ fsw));
            bfr[i] = *(const bf16x8*)((char*)Bl + (wc*64 + i*16 + li)*128 + ((kk*64 + gg*16) ^ fsw));
        }
        __builtin_amdgcn_s_setprio(1);
        #pragma unroll
        for (int i = 0; i < 4; i++)
            #pragma unroll
            for (int j = 0; j < 4; j++)
                acc[i][j] = __builtin_amdgcn_mfma_f32_16x16x32_bf16(af[i], bfr[j], acc[i][j], 0, 0, 0);
        __builtin_amdgcn_s_setprio(0);
    }

    bf16* Sb = S + (size_t)bo * NQ * NKV;
    #pragma unroll
    for (int i = 0; i < 4; i++) {
        #pragma unroll
        for (int j = 0; j < 4; j++) {
            int rbase = m0 + wr*64 + i*16 + gg*4;
            int c     = n0 + wc*64 + j*16 + li;
            #pragma unroll
            for (int jj = 0; jj < 4; jj++)
                Sb[(size_t)(rbase + jj) * NKV + c] = (bf16)acc[i][j][jj];
        }
    }
}

// ---------------- mix + softmax + dev + ssq (streaming, IN-PLACE on S) ----------------
// R14's exact verified form: grid (144, CB); 256 thr = 4 waves; wave = 4 q-rows.
__global__ __launch_bounds__(256) void mix_softmax(
    bf16* __restrict__ S, const float* __restrict__ twf,
    float* __restrict__ ssq_g, int b0)
{
    const int t = threadIdx.x;
    const int lane = t & 63, w = t >> 6;
    const int bl = blockIdx.y;
    const int b  = b0 + bl;
    const int q0 = blockIdx.x * 16 + w * 4;
    __shared__ float rpar[4][8];

    float tw[8][8];
    #pragma unroll
    for (int o = 0; o < 8; o++)
        #pragma unroll
        for (int i = 0; i < 8; i++)
            tw[o][i] = twf[o*8 + i];     // uniform address -> scalar load

    float ssqL[8] = {};
    for (int qi = 0; qi < 4; qi++) {
        float s[8][4];
        #pragma unroll
        for (int i = 0; i < 8; i++) {
            bf16x4 v = *(const bf16x4*)(S + (((size_t)(bl*8 + i))*NQ + (q0 + qi))*NKV + lane*4);
            #pragma unroll
            for (int r = 0; r < 4; r++) s[i][r] = (float)v[r];
        }
        float e[8][4], inv[8];
        #pragma unroll
        for (int o = 0; o < 8; o++) {
            float sum = 0.f;
            #pragma unroll
            for (int r = 0; r < 4; r++) {
                float a = 0.f;
                #pragma unroll
                for (int i = 0; i < 8; i++) a += tw[o][i] * s[i][r];
                e[o][r] = __expf(a);
                sum += e[o][r];
            }
            #pragma unroll
            for (int m = 1; m < 64; m <<= 1) sum += __shfl_xor(sum, m);
            inv[o] = 1.0f / sum;
        }
        #pragma unroll
        for (int o = 0; o < 8; o++) {
            bf16x4 dv;
            #pragma unroll
            for (int r = 0; r < 4; r++) {
                float d = e[o][r] * inv[o] - (1.0f/256.0f);
                ssqL[o] += d * d;
                dv[r] = (bf16)d;
            }
            *(bf16x4*)(S + (((size_t)(bl*8 + o))*NQ + (q0 + qi))*NKV + lane*4) = dv;
        }
    }
    #pragma unroll
    for (int o = 0; o < 8; o++) {
        float s = ssqL[o];
        #pragma unroll
        for (int m = 1; m < 64; m <<= 1) s += __shfl_xor(s, m);
        if (lane == 0) rpar[w][o] = s;
    }
    __syncthreads();
    if (t < 8) {
        float tot = rpar[0][t] + rpar[1][t] + rpar[2][t] + rpar[3][t];
        atomicAdd(&ssq_g[b*8 + t], tot);
    }
}

// ---------------- PV-GEMM: U[b,o-cols] = Dev[plane] @ V[b,o]  (M=2304,N=64,K=256) ----
__global__ __launch_bounds__(256) void gemm_pv(
    const bf16* __restrict__ Dev, const bf16* __restrict__ VT, bf16* __restrict__ U,
    int b0)
{
    __shared__ bf16 Al[128 * 64];
    __shared__ bf16 Bl[64 * 64];
    const int m0 = blockIdx.x * 128;
    const int bo = blockIdx.y;
    const int b = b0 + (bo >> 3), o = bo & 7;
    const int t = threadIdx.x;
    const int lane = t & 63, w = t >> 6;
    const int wr = w >> 1, wc = w & 1;
    const int gg = lane >> 4, li = lane & 15;
    const int fsw = (li & 7) << 4;

    const bf16* Ab = Dev + (size_t)bo * NQ * NKV;
    const bf16* Bb = VT + ((size_t)(b*8 + o)) * 64 * NKV;

    f32x4 acc[4][2] = {};

    for (int k0 = 0; k0 < 256; k0 += 64) {
        #pragma unroll
        for (int p = 0; p < 4; p++) {
            int off = p*4096 + t*16;
            int row = off >> 7;
            int col = ((((off >> 4) & 7) ^ (row & 7)) << 3);
            gload_lds16(Ab + (size_t)(m0 + row)*NKV + k0 + col, (char*)Al + off);
        }
        #pragma unroll
        for (int p = 0; p < 2; p++) {
            int off = p*4096 + t*16;
            int row = off >> 7;
            int col = ((((off >> 4) & 7) ^ (row & 7)) << 3);
            gload_lds16(Bb + (size_t)row*NKV + k0 + col, (char*)Bl + off);
        }
        __syncthreads();
        #pragma unroll
        for (int kk = 0; kk < 2; kk++) {
            bf16x8 af[4], bfr[2];
            #pragma unroll
            for (int i = 0; i < 4; i++)
                af[i] = *(const bf16x8*)((char*)Al + (wr*64 + i*16 + li)*128 + ((kk*64 + gg*16) ^ fsw));
            #pragma unroll
            for (int j = 0; j < 2; j++)
                bfr[j] = *(const bf16x8*)((char*)Bl + (wc*32 + j*16 + li)*128 + ((kk*64 + gg*16) ^ fsw));
            __builtin_amdgcn_s_setprio(1);
            #pragma unroll
            for (int i = 0; i < 4; i++)
                #pragma unroll
                for (int j = 0; j < 2; j++)
                    acc[i][j] = __builtin_amdgcn_mfma_f32_16x16x32_bf16(af[i], bfr[j], acc[i][j], 0, 0, 0);
            __builtin_amdgcn_s_setprio(0);
        }
        __syncthreads();
    }

    #pragma unroll
    for (int i = 0; i < 4; i++) {
        #pragma unroll
        for (int j = 0; j < 2; j++) {
            int rbase = m0 + wr*64 + i*16 + gg*4;
            int c = wc*32 + j*16 + li;
            #pragma unroll
            for (int jj = 0; jj < 4; jj++)
                U[((size_t)b*NQ + rbase + jj)*DD + o*64 + c] = (bf16)acc[i][j][jj];
        }
    }
}

// ---------------- per-batch scaled Wo^T ----------------
__global__ __launch_bounds__(256) void scale_wot(const bf16* __restrict__ WoT,
                                                 const float* __restrict__ ssq,
                                                 bf16* __restrict__ out)
{
    int idx = blockIdx.x * 256 + threadIdx.x;
    int c8 = idx & 63;
    int c  = (idx >> 6) & 511;
    int b  = idx >> 15;
    int h  = c8 >> 3;
    float va = ssq[b*8 + h] * (1.0f / ((float)NQ * (float)NKV));
    float s  = rsqrtf(va + 1e-5f);
    bf16x8 v = *(const bf16x8*)(WoT + ((size_t)c << 9) + c8*8);
    bf16x8 r;
    #pragma unroll
    for (int i = 0; i < 8; i++) r[i] = (bf16)((float)v[i] * s);
    *(bf16x8*)(out + ((size_t)idx << 3)) = r;
}

// ======================================================================
extern "C" void kernel_launch(void* const* d_in, const int* in_sizes, int n_in,
                              void* d_out, int out_size, void* d_ws, size_t ws_size,
                              hipStream_t stream)
{
    const void* queries = d_in[0];
    const void* Wq = d_in[1];  const void* bq = d_in[2];
    const void* Wk = d_in[3];  const void* bk = d_in[4];
    const void* Wv = d_in[5];  const void* bv = d_in[6];
    const void* Wo = d_in[7];  const void* bo = d_in[8];
    const void* srw = d_in[9]; const void* srb = d_in[10];
    const void* lng = d_in[11]; const void* lnb = d_in[12];
    const void* tw  = d_in[13];
    // d_in[14] = tb: cancels in softmax; unused.

    char* ws = (char*)d_ws;
    bf16* WqT = (bf16*)(ws + OFF_WQT);
    bf16* WkT = (bf16*)(ws + OFF_WKT);
    bf16* WvT = (bf16*)(ws + OFF_WVT);
    bf16* WoT = (bf16*)(ws + OFF_WOT);
    bf16* xb  = (bf16*)(ws + OFF_X);
    bf16* Kt  = (bf16*)(ws + OFF_KT);
    bf16* VTb = (bf16*)(ws + OFF_VT);
    bf16* Qf  = (bf16*)(ws + OFF_QF);
    bf16* Ub  = (bf16*)(ws + OFF_U);
    float* ss = (float*)(ws + OFF_SS);
    bf16* sm  = (bf16*)(ws + OFF_SM);
    float* twf = (float*)(ws + OFF_TWF);
    int* flag = (int*)(ws + OFF_FLG);
    bf16* WoTp = (bf16*)(ws + OFF_WOTP);
    bf16* Sb  = (bf16*)(ws + OFF_S);       // S/Dev chunk buffer (in-place mix)

    // chunk size: largest CB that fits (R7 proved CB=16 fits this harness)
    int CB = 1;
    if      (OFF_S + 16*8*SPLANE <= ws_size) CB = 16;
    else if (OFF_S +  8*8*SPLANE <= ws_size) CB = 8;
    else if (OFF_S +  4*8*SPLANE <= ws_size) CB = 4;
    else if (OFF_S +  2*8*SPLANE <= ws_size) CB = 2;

    detect_dtype<<<dim3(1), dim3(64), 0, stream>>>((const uint32_t*)queries, flag);
    hipMemsetAsync(ss, 0, 128 * sizeof(float), stream);

    convert_small<<<dim3(9), dim3(256), 0, stream>>>(bq, bk, bv, bo, srw, srb, lng, lnb, tw, sm, twf, flag);
    transpose512<<<dim3(16, 16, 4), dim3(32, 8), 0, stream>>>(Wq, Wk, Wv, Wo, WqT, WkT, WvT, WoT, flag);

    sr_ln<<<dim3(NB * NKV / 4), dim3(256), 0, stream>>>(queries, sm, xb, flag);
    gemm_bt<0><<<dim3(32, 4), dim3(256), 0, stream>>>(xb, WkT, sm + SM_BK, Kt, nullptr);
    gemm_bt<1><<<dim3(32, 4), dim3(256), 0, stream>>>(xb, WvT, sm + SM_BV, VTb, nullptr);
    gemm_bt<4><<<dim3(288, 4), dim3(256), 0, stream>>>((const bf16*)queries, WqT, sm + SM_BQ, Qf, flag);

    for (int b0 = 0; b0 < NB; b0 += CB) {
        gemm_s<<<dim3(18, 2, CB*8), dim3(256), 0, stream>>>(Qf, Kt, Sb, b0);
        mix_softmax<<<dim3(144, CB), dim3(256), 0, stream>>>(Sb, twf, ss, b0);
        gemm_pv<<<dim3(18, CB*8), dim3(256), 0, stream>>>(Sb, VTb, Ub, b0);
    }

    scale_wot<<<dim3(2048), dim3(256), 0, stream>>>(WoT, ss, WoTp);
    gemm_bt<2><<<dim3(288, 4), dim3(256), 0, stream>>>(Ub, WoTp, sm + SM_BO, (bf16*)d_out, flag);
}

// Round 18
// 288.562 us; speedup vs baseline: 1.0855x; 1.0651x over previous
//
#include <hip/hip_runtime.h>
#include <hip/hip_bf16.h>
#include <stdint.h>

// ======================================================================
// EMSA fused pipeline. Device dtype (bf16 vs f32) detected at runtime.
// Algebra:
//  * S_i = Q_i K_i^T /8 once per input head (9.7 GF); head-mix tw applied
//    in a streaming VALU kernel; PV is a clean batched GEMM.
//  * softmax row-sums are 1  =>  instance-norm mean = 1/256 exactly
//  * Dev = P - 1/256; var = mean(Dev^2); out = (Dev@V)*rsqrt(va+eps)
//  * tb cancels in softmax; 1/sqrt(dk) folded into WqT/bq.
//  * instance-norm scale folded into gemm_pv's EPILOGUE (sigma is
//    per-(b,o) = exactly gemm_pv's block granularity; ssq complete by
//    same-stream ordering) -> scale_wot kernel + WoTp buffer deleted.
// R18: base = R14 (best green 294.6us). R17's convert_q elimination
//     regressed (+13us: lost async staging, 2x Q-GEMM fetch) - reverted.
// ======================================================================

typedef __bf16 bf16;
typedef __bf16 bf16x4 __attribute__((ext_vector_type(4)));
typedef __bf16 bf16x8 __attribute__((ext_vector_type(8)));
typedef float  f32x4  __attribute__((ext_vector_type(4)));

#define LDS_AS  __attribute__((address_space(3)))
#define GLOB_AS __attribute__((address_space(1)))

__device__ __forceinline__ void gload_lds16(const bf16* g, void* l) {
    __builtin_amdgcn_global_load_lds((const GLOB_AS void*)g, (LDS_AS void*)l, 16, 0, 0);
}

// ---------------- constants ----------------
#define NB   16
#define NQ   2304
#define DD   512
#define NKV  256

// workspace layout (bytes)
constexpr size_t OFF_WQT = 0;
constexpr size_t OFF_WKT = 512*512*2;
constexpr size_t OFF_WVT = 2*512*512*2;
constexpr size_t OFF_WOT = 3*512*512*2;
constexpr size_t OFF_X   = 4*512*512*2;
constexpr size_t OFF_KT  = OFF_X  + 4194304;
constexpr size_t OFF_VT  = OFF_KT + 4194304;
constexpr size_t OFF_SS  = OFF_VT + 4194304;
constexpr size_t OFF_SM  = OFF_SS + 512;
constexpr size_t OFF_TWF = OFF_SM + 40192;               // SM incl. srwT
constexpr size_t OFF_FLG = OFF_TWF + 256;
constexpr size_t OFF_QF  = OFF_FLG + 256;
constexpr size_t OFF_U   = OFF_QF + (size_t)NB*NQ*DD*2;
constexpr size_t OFF_S   = OFF_U  + (size_t)NB*NQ*DD*2;   // S/Dev chunk buffer
constexpr size_t SPLANE  = (size_t)NQ*NKV*2;

// small-region element offsets
#define SM_BQ   0
#define SM_BK   512
#define SM_BV   1024
#define SM_BO   1536
#define SM_SRW  2048
#define SM_SRB  10240
#define SM_LNG  10752
#define SM_LNB  11264
#define SM_TW   11776
#define SM_SRWT 11840   /* [tap][ch] transposed depthwise weights, 16x512 */

// ---------------- dtype detection ----------------
__global__ __launch_bounds__(64) void detect_dtype(const uint32_t* __restrict__ q,
                                                   int* __restrict__ flag)
{
    int t = threadIdx.x;
    int cnt = 0;
    #pragma unroll
    for (int i = 0; i < 8; i++) {
        uint32_t w = q[t*8 + i];
        int e = (w >> 7) & 0xFF;
        cnt += (e >= 100 && e <= 150) ? 1 : 0;
    }
    #pragma unroll
    for (int m = 1; m < 64; m <<= 1) cnt += __shfl_xor(cnt, m);
    if (t == 0) *flag = (cnt >= 384) ? 0 : 1;   // 0=bf16, 1=f32
}

// ---------------- input conversion (work only for f32 input) ----------------
__global__ __launch_bounds__(256) void convert_q(const void* __restrict__ in,
                                                 bf16* __restrict__ out,
                                                 const int* __restrict__ flag)
{
    if (*flag == 0) return;
    int idx = blockIdx.x * 256 + threadIdx.x;
    f32x4 a = ((const f32x4*)in)[(size_t)idx*2];
    f32x4 b = ((const f32x4*)in)[(size_t)idx*2 + 1];
    bf16x8 r;
    #pragma unroll
    for (int i = 0; i < 4; i++) { r[i] = (bf16)a[i]; r[i+4] = (bf16)b[i]; }
    ((bf16x8*)out)[idx] = r;
}

__global__ __launch_bounds__(256) void convert_small(
    const void* s0, const void* s1, const void* s2, const void* s3,
    const void* s4, const void* s5, const void* s6, const void* s7,
    const void* s8, bf16* __restrict__ dst, float* __restrict__ twf,
    const int* __restrict__ flag)
{
    const void* srcs[9] = {s0,s1,s2,s3,s4,s5,s6,s7,s8};
    const int sizes[9]  = {512,512,512,512,8192,512,512,512,64};
    const int offs[9]   = {SM_BQ,SM_BK,SM_BV,SM_BO,SM_SRW,SM_SRB,SM_LNG,SM_LNB,SM_TW};
    const float scl[9]  = {0.125f,1.f,1.f,1.f,1.f,1.f,1.f,1.f,1.f};
    int b = blockIdx.x;
    const void* s = srcs[b];
    int n = sizes[b], o = offs[b];
    float sc = scl[b];
    bool f32 = (*flag != 0);
    for (int i = threadIdx.x; i < n; i += 256) {
        float v = f32 ? ((const float*)s)[i] : (float)((const bf16*)s)[i];
        dst[o + i] = (bf16)(v * sc);
        if (b == 8) twf[i] = v;
        if (b == 4) {
            // transposed copy: srw is [ch][tap] (i = ch*16 + tap)
            int tap = i & 15, ch = i >> 4;
            dst[SM_SRWT + tap*DD + ch] = (bf16)v;
        }
    }
}

// ---------------- weight transpose (512x512) ----------------
__global__ __launch_bounds__(256) void transpose512(
    const void* s0, const void* s1, const void* s2, const void* s3,
    bf16* __restrict__ d0, bf16* __restrict__ d1,
    bf16* __restrict__ d2, bf16* __restrict__ d3,
    const int* __restrict__ flag)
{
    __shared__ bf16 tile[32][33];
    bool f32 = (*flag != 0);
    int wsel = blockIdx.z;
    const void* src = wsel == 0 ? s0 : wsel == 1 ? s1 : wsel == 2 ? s2 : s3;
    bf16*       dst = wsel == 0 ? d0 : wsel == 1 ? d1 : wsel == 2 ? d2 : d3;
    float scl = (wsel == 0) ? 0.125f : 1.0f;
    int c0 = blockIdx.x * 32, n0 = blockIdx.y * 32;
    int tx = threadIdx.x, ty = threadIdx.y;
    #pragma unroll
    for (int i = 0; i < 4; i++) {
        size_t idx = (size_t)(c0 + ty + i*8) * 512 + n0 + tx;
        float v = f32 ? ((const float*)src)[idx] : (float)((const bf16*)src)[idx];
        tile[ty + i*8][tx] = (bf16)(v * scl);
    }
    __syncthreads();
    #pragma unroll
    for (int i = 0; i < 4; i++)
        dst[(size_t)(n0 + ty + i*8) * 512 + c0 + tx] = tile[tx][ty + i*8];
}

// ---------------- depthwise 4x4/s3 conv + LayerNorm (wave-per-output) ------------
__global__ __launch_bounds__(256) void sr_ln(
    const void* __restrict__ qraw, const bf16* __restrict__ qc,
    const bf16* __restrict__ sm, bf16* __restrict__ x,
    const int* __restrict__ flag)
{
    const bf16* q = (*flag) ? qc : (const bf16*)qraw;
    const int t = threadIdx.x;
    const int w = t >> 6, lane = t & 63;
    const int pos = blockIdx.x * 4 + w;        // b*256 + ok
    const int b = pos >> 8, ok = pos & 255;
    const int oh = ok >> 4, ow = ok & 15;
    const int c0 = lane * 8;

    float acc[8] = {};
    #pragma unroll
    for (int kh = 0; kh < 4; kh++) {
        int ih = oh*3 - 1 + kh;
        if (ih < 0) continue;
        #pragma unroll
        for (int kw = 0; kw < 4; kw++) {
            int iw = ow*3 - 1 + kw;
            if (iw < 0) continue;
            bf16x8 qv = *(const bf16x8*)(q + ((size_t)b*NQ + ih*48 + iw)*DD + c0);
            bf16x8 wv = *(const bf16x8*)(sm + SM_SRWT + (kh*4 + kw)*DD + c0);
            #pragma unroll
            for (int r = 0; r < 8; r++) acc[r] += (float)qv[r] * (float)wv[r];
        }
    }
    bf16x8 sb = *(const bf16x8*)(sm + SM_SRB + c0);
    #pragma unroll
    for (int r = 0; r < 8; r++) acc[r] += (float)sb[r];

    float s = 0.f, s2 = 0.f;
    #pragma unroll
    for (int r = 0; r < 8; r++) { s += acc[r]; s2 += acc[r]*acc[r]; }
    #pragma unroll
    for (int m = 1; m < 64; m <<= 1) { s += __shfl_xor(s, m); s2 += __shfl_xor(s2, m); }
    float mu  = s * (1.f/512.f);
    float var = s2 * (1.f/512.f) - mu*mu;
    float inv = rsqrtf(var + 1e-5f);

    bf16x8 gv = *(const bf16x8*)(sm + SM_LNG + c0);
    bf16x8 bv = *(const bf16x8*)(sm + SM_LNB + c0);
    bf16x8 outv;
    #pragma unroll
    for (int r = 0; r < 8; r++)
        outv[r] = (bf16)((acc[r] - mu) * inv * (float)gv[r] + (float)bv[r]);
    *(bf16x8*)(x + (size_t)pos * DD + c0) = outv;
}

// ---------------- generic BT-GEMM: C(M,512) = A(M,512) @ Bt(512,512)^T + bias ----------
// MODE 0: bf16 row-major store. MODE 1: V^T scatter store (b,h,dv,kk).
// MODE 2: output GEMM (plain WoT, dtype-branch store).
// MODE 4: A chosen by flag (raw vs converted queries).
template <int MODE>
__global__ __launch_bounds__(256) void gemm_bt(
    const bf16* __restrict__ A, const bf16* __restrict__ Bt,
    const bf16* __restrict__ bias, bf16* __restrict__ C,
    const int* __restrict__ of32, const bf16* __restrict__ A2)
{
    constexpr int K = 512;
    __shared__ bf16 Al[128 * 64];
    __shared__ bf16 Bl[128 * 64];
    const int m0 = blockIdx.x * 128, n0 = blockIdx.y * 128;
    const int t = threadIdx.x;
    const int lane = t & 63, w = t >> 6;
    const int wr = w >> 1, wc = w & 1;
    const int gg = lane >> 4, li = lane & 15;
    const int fsw = (li & 7) << 4;
    bool f32o = false;
    if (MODE == 2 || MODE == 4) f32o = (*of32 != 0);

    const bf16* Ab = A;
    if (MODE == 4) Ab = f32o ? A2 : A;

    f32x4 acc[4][4] = {};

    for (int k0 = 0; k0 < K; k0 += 64) {
        #pragma unroll
        for (int p = 0; p < 4; p++) {
            int off = p*4096 + t*16;
            int row = off >> 7;
            int col = ((((off >> 4) & 7) ^ (row & 7)) << 3);
            gload_lds16(Ab + (size_t)(m0 + row)*K + k0 + col, (char*)Al + off);
        }
        #pragma unroll
        for (int p = 0; p < 4; p++) {
            int off = p*4096 + t*16;
            int row = off >> 7;
            int col = ((((off >> 4) & 7) ^ (row & 7)) << 3);
            gload_lds16(Bt + (size_t)(n0 + row)*K + k0 + col, (char*)Bl + off);
        }
        __syncthreads();
        #pragma unroll
        for (int kk = 0; kk < 2; kk++) {
            bf16x8 af[4], bfr[4];
            #pragma unroll
            for (int i = 0; i < 4; i++) {
                af[i]  = *(const bf16x8*)((char*)Al + (wr*64 + i*16 + li)*128 + ((kk*64 + gg*16) ^ fsw));
                bfr[i] = *(const bf16x8*)((char*)Bl + (wc*64 + i*16 + li)*128 + ((kk*64 + gg*16) ^ fsw));
            }
            __builtin_amdgcn_s_setprio(1);
            #pragma unroll
            for (int i = 0; i < 4; i++)
                #pragma unroll
                for (int j = 0; j < 4; j++)
                    acc[i][j] = __builtin_amdgcn_mfma_f32_16x16x32_bf16(af[i], bfr[j], acc[i][j], 0, 0, 0);
            __builtin_amdgcn_s_setprio(0);
        }
        __syncthreads();
    }

    #pragma unroll
    for (int i = 0; i < 4; i++) {
        #pragma unroll
        for (int j = 0; j < 4; j++) {
            int rbase = m0 + wr*64 + i*16 + gg*4;
            int c     = n0 + wc*64 + j*16 + li;
            float bv = (float)bias[c];
            #pragma unroll
            for (int jj = 0; jj < 4; jj++) {
                float val = acc[i][j][jj] + bv;
                int r = rbase + jj;
                if (MODE == 1) {
                    int bb = r >> 8, kk2 = r & 255;
                    int hh = c >> 6, dv = c & 63;
                    C[(((size_t)(bb*8 + hh))*64 + dv)*256 + kk2] = (bf16)val;
                } else if (MODE == 2) {
                    if (f32o) ((float*)C)[(size_t)r * 512 + c] = val;
                    else      C[(size_t)r * 512 + c] = (bf16)val;
                } else {
                    C[(size_t)r * 512 + c] = (bf16)val;
                }
            }
        }
    }
}

// ---------------- S-GEMM: S[plane] = Q_i @ K_i^T  (M=2304,N=256,K=64) ----------------
__global__ __launch_bounds__(256) void gemm_s(
    const bf16* __restrict__ Qf, const bf16* __restrict__ Kt, bf16* __restrict__ S,
    int b0)
{
    __shared__ bf16 Al[128 * 64];
    __shared__ bf16 Bl[128 * 64];
    const int m0 = blockIdx.x * 128, n0 = blockIdx.y * 128;
    const int bo = blockIdx.z;
    const int b = b0 + (bo >> 3), ih = bo & 7;
    const int t = threadIdx.x;
    const int lane = t & 63, w = t >> 6;
    const int wr = w >> 1, wc = w & 1;
    const int gg = lane >> 4, li = lane & 15;
    const int fsw = (li & 7) << 4;

    #pragma unroll
    for (int p = 0; p < 4; p++) {
        int off = p*4096 + t*16;
        int row = off >> 7;
        int col = ((((off >> 4) & 7) ^ (row & 7)) << 3);
        gload_lds16(Qf + ((size_t)(b*NQ + m0 + row))*DD + ih*64 + col, (char*)Al + off);
    }
    #pragma unroll
    for (int p = 0; p < 4; p++) {
        int off = p*4096 + t*16;
        int row = off >> 7;
        int col = ((((off >> 4) & 7) ^ (row & 7)) << 3);
        gload_lds16(Kt + ((size_t)(b*NKV + n0 + row))*DD + ih*64 + col, (char*)Bl + off);
    }
    __syncthreads();

    f32x4 acc[4][4] = {};
    #pragma unroll
    for (int kk = 0; kk < 2; kk++) {
        bf16x8 af[4], bfr[4];
        #pragma unroll
        for (int i = 0; i < 4; i++) {
            af[i]  = *(const bf16x8*)((char*)Al + (wr*64 + i*16 + li)*128 + ((kk*64 + gg*16) ^ fsw));
            bfr[i] = *(const bf16x8*)((char*)Bl + (wc*64 + i*16 + li)*128 + ((kk*64 + gg*16) ^ fsw));
        }
        __builtin_amdgcn_s_setprio(1);
        #pragma unroll
        for (int i = 0; i < 4; i++)
            #pragma unroll
            for (int j = 0; j < 4; j++)
                acc[i][j] = __builtin_amdgcn_mfma_f32_16x16x32_bf16(af[i], bfr[j], acc[i][j], 0, 0, 0);
        __builtin_amdgcn_s_setprio(0);
    }

    bf16* Sb = S + (size_t)bo * NQ * NKV;
    #pragma unroll
    for (int i = 0; i < 4; i++) {
        #pragma unroll
        for (int j = 0; j < 4; j++) {
            int rbase = m0 + wr*64 + i*16 + gg*4;
            int c     = n0 + wc*64 + j*16 + li;
            #pragma unroll
            for (int jj = 0; jj < 4; jj++)
                Sb[(size_t)(rbase + jj) * NKV + c] = (bf16)acc[i][j][jj];
        }
    }
}

// ---------------- mix + softmax + dev + ssq (streaming, IN-PLACE on S) ----------------
// R14's exact verified form: grid (144, CB); 256 thr = 4 waves; wave = 4 q-rows.
__global__ __launch_bounds__(256) void mix_softmax(
    bf16* __restrict__ S, const float* __restrict__ twf,
    float* __restrict__ ssq_g, int b0)
{
    const int t = threadIdx.x;
    const int lane = t & 63, w = t >> 6;
    const int bl = blockIdx.y;
    const int b  = b0 + bl;
    const int q0 = blockIdx.x * 16 + w * 4;
    __shared__ float rpar[4][8];

    float tw[8][8];
    #pragma unroll
    for (int o = 0; o < 8; o++)
        #pragma unroll
        for (int i = 0; i < 8; i++)
            tw[o][i] = twf[o*8 + i];     // uniform address -> scalar load

    float ssqL[8] = {};
    for (int qi = 0; qi < 4; qi++) {
        float s[8][4];
        #pragma unroll
        for (int i = 0; i < 8; i++) {
            bf16x4 v = *(const bf16x4*)(S + (((size_t)(bl*8 + i))*NQ + (q0 + qi))*NKV + lane*4);
            #pragma unroll
            for (int r = 0; r < 4; r++) s[i][r] = (float)v[r];
        }
        float e[8][4], inv[8];
        #pragma unroll
        for (int o = 0; o < 8; o++) {
            float sum = 0.f;
            #pragma unroll
            for (int r = 0; r < 4; r++) {
                float a = 0.f;
                #pragma unroll
                for (int i = 0; i < 8; i++) a += tw[o][i] * s[i][r];
                e[o][r] = __expf(a);
                sum += e[o][r];
            }
            #pragma unroll
            for (int m = 1; m < 64; m <<= 1) sum += __shfl_xor(sum, m);
            inv[o] = 1.0f / sum;
        }
        #pragma unroll
        for (int o = 0; o < 8; o++) {
            bf16x4 dv;
            #pragma unroll
            for (int r = 0; r < 4; r++) {
                float d = e[o][r] * inv[o] - (1.0f/256.0f);
                ssqL[o] += d * d;
                dv[r] = (bf16)d;
            }
            *(bf16x4*)(S + (((size_t)(bl*8 + o))*NQ + (q0 + qi))*NKV + lane*4) = dv;
        }
    }
    #pragma unroll
    for (int o = 0; o < 8; o++) {
        float s = ssqL[o];
        #pragma unroll
        for (int m = 1; m < 64; m <<= 1) s += __shfl_xor(s, m);
        if (lane == 0) rpar[w][o] = s;
    }
    __syncthreads();
    if (t < 8) {
        float tot = rpar[0][t] + rpar[1][t] + rpar[2][t] + rpar[3][t];
        atomicAdd(&ssq_g[b*8 + t], tot);
    }
}

// ---------------- PV-GEMM: U = (Dev @ V) * rsqrt(var+eps), per (b,o) plane --------
// ssq_g[b*8+o] is complete before this launches (same-stream ordering).
__global__ __launch_bounds__(256) void gemm_pv(
    const bf16* __restrict__ Dev, const bf16* __restrict__ VT, bf16* __restrict__ U,
    const float* __restrict__ ssq_g, int b0)
{
    __shared__ bf16 Al[128 * 64];
    __shared__ bf16 Bl[64 * 64];
    const int m0 = blockIdx.x * 128;
    const int bo = blockIdx.y;
    const int b = b0 + (bo >> 3), o = bo & 7;
    const int t = threadIdx.x;
    const int lane = t & 63, w = t >> 6;
    const int wr = w >> 1, wc = w & 1;
    const int gg = lane >> 4, li = lane & 15;
    const int fsw = (li & 7) << 4;

    const bf16* Ab = Dev + (size_t)bo * NQ * NKV;
    const bf16* Bb = VT + ((size_t)(b*8 + o)) * 64 * NKV;
    const float sc = rsqrtf(ssq_g[b*8 + o] * (1.0f / ((float)NQ * (float)NKV)) + 1e-5f);

    f32x4 acc[4][2] = {};

    for (int k0 = 0; k0 < 256; k0 += 64) {
        #pragma unroll
        for (int p = 0; p < 4; p++) {
            int off = p*4096 + t*16;
            int row = off >> 7;
            int col = ((((off >> 4) & 7) ^ (row & 7)) << 3);
            gload_lds16(Ab + (size_t)(m0 + row)*NKV + k0 + col, (char*)Al + off);
        }
        #pragma unroll
        for (int p = 0; p < 2; p++) {
            int off = p*4096 + t*16;
            int row = off >> 7;
            int col = ((((off >> 4) & 7) ^ (row & 7)) << 3);
            gload_lds16(Bb + (size_t)row*NKV + k0 + col, (char*)Bl + off);
        }
        __syncthreads();
        #pragma unroll
        for (int kk = 0; kk < 2; kk++) {
            bf16x8 af[4], bfr[2];
            #pragma unroll
            for (int i = 0; i < 4; i++)
                af[i] = *(const bf16x8*)((char*)Al + (wr*64 + i*16 + li)*128 + ((kk*64 + gg*16) ^ fsw));
            #pragma unroll
            for (int j = 0; j < 2; j++)
                bfr[j] = *(const bf16x8*)((char*)Bl + (wc*32 + j*16 + li)*128 + ((kk*64 + gg*16) ^ fsw));
            __builtin_amdgcn_s_setprio(1);
            #pragma unroll
            for (int i = 0; i < 4; i++)
                #pragma unroll
                for (int j = 0; j < 2; j++)
                    acc[i][j] = __builtin_amdgcn_mfma_f32_16x16x32_bf16(af[i], bfr[j], acc[i][j], 0, 0, 0);
            __builtin_amdgcn_s_setprio(0);
        }
        __syncthreads();
    }

    #pragma unroll
    for (int i = 0; i < 4; i++) {
        #pragma unroll
        for (int j = 0; j < 2; j++) {
            int rbase = m0 + wr*64 + i*16 + gg*4;
            int c = wc*32 + j*16 + li;
            #pragma unroll
            for (int jj = 0; jj < 4; jj++)
                U[((size_t)b*NQ + rbase + jj)*DD + o*64 + c] = (bf16)(acc[i][j][jj] * sc);
        }
    }
}

// ======================================================================
extern "C" void kernel_launch(void* const* d_in, const int* in_sizes, int n_in,
                              void* d_out, int out_size, void* d_ws, size_t ws_size,
                              hipStream_t stream)
{
    const void* queries = d_in[0];
    const void* Wq = d_in[1];  const void* bq = d_in[2];
    const void* Wk = d_in[3];  const void* bk = d_in[4];
    const void* Wv = d_in[5];  const void* bv = d_in[6];
    const void* Wo = d_in[7];  const void* bo = d_in[8];
    const void* srw = d_in[9]; const void* srb = d_in[10];
    const void* lng = d_in[11]; const void* lnb = d_in[12];
    const void* tw  = d_in[13];
    // d_in[14] = tb: cancels in softmax; unused.

    char* ws = (char*)d_ws;
    bf16* WqT = (bf16*)(ws + OFF_WQT);
    bf16* WkT = (bf16*)(ws + OFF_WKT);
    bf16* WvT = (bf16*)(ws + OFF_WVT);
    bf16* WoT = (bf16*)(ws + OFF_WOT);
    bf16* xb  = (bf16*)(ws + OFF_X);
    bf16* Kt  = (bf16*)(ws + OFF_KT);
    bf16* VTb = (bf16*)(ws + OFF_VT);
    bf16* Qf  = (bf16*)(ws + OFF_QF);
    bf16* Ub  = (bf16*)(ws + OFF_U);
    float* ss = (float*)(ws + OFF_SS);
    bf16* sm  = (bf16*)(ws + OFF_SM);
    float* twf = (float*)(ws + OFF_TWF);
    int* flag = (int*)(ws + OFF_FLG);
    bf16* Sb  = (bf16*)(ws + OFF_S);       // S/Dev chunk buffer (in-place mix)
    bf16* Qc  = Ub;                        // converted queries (f32 path)

    // chunk size: largest CB that fits (R7 proved CB=16 fits this harness)
    int CB = 1;
    if      (OFF_S + 16*8*SPLANE <= ws_size) CB = 16;
    else if (OFF_S +  8*8*SPLANE <= ws_size) CB = 8;
    else if (OFF_S +  4*8*SPLANE <= ws_size) CB = 4;
    else if (OFF_S +  2*8*SPLANE <= ws_size) CB = 2;

    detect_dtype<<<dim3(1), dim3(64), 0, stream>>>((const uint32_t*)queries, flag);
    hipMemsetAsync(ss, 0, 128 * sizeof(float), stream);

    convert_q<<<dim3(9216), dim3(256), 0, stream>>>(queries, Qc, flag);
    convert_small<<<dim3(9), dim3(256), 0, stream>>>(bq, bk, bv, bo, srw, srb, lng, lnb, tw, sm, twf, flag);
    transpose512<<<dim3(16, 16, 4), dim3(32, 8), 0, stream>>>(Wq, Wk, Wv, Wo, WqT, WkT, WvT, WoT, flag);

    sr_ln<<<dim3(NB * NKV / 4), dim3(256), 0, stream>>>(queries, Qc, sm, xb, flag);
    gemm_bt<0><<<dim3(32, 4), dim3(256), 0, stream>>>(xb, WkT, sm + SM_BK, Kt, nullptr, nullptr);
    gemm_bt<1><<<dim3(32, 4), dim3(256), 0, stream>>>(xb, WvT, sm + SM_BV, VTb, nullptr, nullptr);
    gemm_bt<4><<<dim3(288, 4), dim3(256), 0, stream>>>((const bf16*)queries, WqT, sm + SM_BQ, Qf, flag, Qc);

    for (int b0 = 0; b0 < NB; b0 += CB) {
        gemm_s<<<dim3(18, 2, CB*8), dim3(256), 0, stream>>>(Qf, Kt, Sb, b0);
        mix_softmax<<<dim3(144, CB), dim3(256), 0, stream>>>(Sb, twf, ss, b0);
        gemm_pv<<<dim3(18, CB*8), dim3(256), 0, stream>>>(Sb, VTb, Ub, ss, b0);
    }

    gemm_bt<2><<<dim3(288, 4), dim3(256), 0, stream>>>(Ub, WoT, sm + SM_BO, (bf16*)d_out, flag, nullptr);
}

// Round 19
// 286.533 us; speedup vs baseline: 1.0932x; 1.0071x over previous
//
#include <hip/hip_runtime.h>
#include <hip/hip_bf16.h>
#include <stdint.h>

// ======================================================================
// EMSA fused pipeline. Device dtype (bf16 vs f32) detected at runtime.
// Algebra:
//  * S_i = Q_i K_i^T /8 once per input head (9.7 GF); head-mix tw applied
//    in a streaming VALU kernel; PV is a clean batched GEMM.
//  * softmax row-sums are 1  =>  instance-norm mean = 1/256 exactly
//  * Dev = P - 1/256; var = mean(Dev^2); out = (Dev@V)*rsqrt(va+eps)
//  * tb cancels in softmax; 1/sqrt(dk) folded into WqT/bq.
//  * instance-norm scale folded into gemm_pv's epilogue.
//  * log2(e) folded into twf so mix's exp = raw v_exp (2^x).
// R19: base = R18 (best green 288.6us). Single micro-change: exp2 fold
//     in mix (same fold passed correctness in R15; applied here to the
//     UNCHANGED R14/R18 mix body, preserving VGPR-44 liveness).
// ======================================================================

typedef __bf16 bf16;
typedef __bf16 bf16x4 __attribute__((ext_vector_type(4)));
typedef __bf16 bf16x8 __attribute__((ext_vector_type(8)));
typedef float  f32x4  __attribute__((ext_vector_type(4)));

#define LDS_AS  __attribute__((address_space(3)))
#define GLOB_AS __attribute__((address_space(1)))

__device__ __forceinline__ void gload_lds16(const bf16* g, void* l) {
    __builtin_amdgcn_global_load_lds((const GLOB_AS void*)g, (LDS_AS void*)l, 16, 0, 0);
}

// ---------------- constants ----------------
#define NB   16
#define NQ   2304
#define DD   512
#define NKV  256

// workspace layout (bytes)
constexpr size_t OFF_WQT = 0;
constexpr size_t OFF_WKT = 512*512*2;
constexpr size_t OFF_WVT = 2*512*512*2;
constexpr size_t OFF_WOT = 3*512*512*2;
constexpr size_t OFF_X   = 4*512*512*2;
constexpr size_t OFF_KT  = OFF_X  + 4194304;
constexpr size_t OFF_VT  = OFF_KT + 4194304;
constexpr size_t OFF_SS  = OFF_VT + 4194304;
constexpr size_t OFF_SM  = OFF_SS + 512;
constexpr size_t OFF_TWF = OFF_SM + 40192;               // SM incl. srwT
constexpr size_t OFF_FLG = OFF_TWF + 256;
constexpr size_t OFF_QF  = OFF_FLG + 256;
constexpr size_t OFF_U   = OFF_QF + (size_t)NB*NQ*DD*2;
constexpr size_t OFF_S   = OFF_U  + (size_t)NB*NQ*DD*2;   // S/Dev chunk buffer
constexpr size_t SPLANE  = (size_t)NQ*NKV*2;

// small-region element offsets
#define SM_BQ   0
#define SM_BK   512
#define SM_BV   1024
#define SM_BO   1536
#define SM_SRW  2048
#define SM_SRB  10240
#define SM_LNG  10752
#define SM_LNB  11264
#define SM_TW   11776
#define SM_SRWT 11840   /* [tap][ch] transposed depthwise weights, 16x512 */

// ---------------- dtype detection ----------------
__global__ __launch_bounds__(64) void detect_dtype(const uint32_t* __restrict__ q,
                                                   int* __restrict__ flag)
{
    int t = threadIdx.x;
    int cnt = 0;
    #pragma unroll
    for (int i = 0; i < 8; i++) {
        uint32_t w = q[t*8 + i];
        int e = (w >> 7) & 0xFF;
        cnt += (e >= 100 && e <= 150) ? 1 : 0;
    }
    #pragma unroll
    for (int m = 1; m < 64; m <<= 1) cnt += __shfl_xor(cnt, m);
    if (t == 0) *flag = (cnt >= 384) ? 0 : 1;   // 0=bf16, 1=f32
}

// ---------------- input conversion (work only for f32 input) ----------------
__global__ __launch_bounds__(256) void convert_q(const void* __restrict__ in,
                                                 bf16* __restrict__ out,
                                                 const int* __restrict__ flag)
{
    if (*flag == 0) return;
    int idx = blockIdx.x * 256 + threadIdx.x;
    f32x4 a = ((const f32x4*)in)[(size_t)idx*2];
    f32x4 b = ((const f32x4*)in)[(size_t)idx*2 + 1];
    bf16x8 r;
    #pragma unroll
    for (int i = 0; i < 4; i++) { r[i] = (bf16)a[i]; r[i+4] = (bf16)b[i]; }
    ((bf16x8*)out)[idx] = r;
}

__global__ __launch_bounds__(256) void convert_small(
    const void* s0, const void* s1, const void* s2, const void* s3,
    const void* s4, const void* s5, const void* s6, const void* s7,
    const void* s8, bf16* __restrict__ dst, float* __restrict__ twf,
    const int* __restrict__ flag)
{
    const void* srcs[9] = {s0,s1,s2,s3,s4,s5,s6,s7,s8};
    const int sizes[9]  = {512,512,512,512,8192,512,512,512,64};
    const int offs[9]   = {SM_BQ,SM_BK,SM_BV,SM_BO,SM_SRW,SM_SRB,SM_LNG,SM_LNB,SM_TW};
    const float scl[9]  = {0.125f,1.f,1.f,1.f,1.f,1.f,1.f,1.f,1.f};
    int b = blockIdx.x;
    const void* s = srcs[b];
    int n = sizes[b], o = offs[b];
    float sc = scl[b];
    bool f32 = (*flag != 0);
    for (int i = threadIdx.x; i < n; i += 256) {
        float v = f32 ? ((const float*)s)[i] : (float)((const bf16*)s)[i];
        dst[o + i] = (bf16)(v * sc);
        if (b == 8) twf[i] = v * 1.44269504088896341f;   // fold log2(e): exp(a)=2^(a')
        if (b == 4) {
            // transposed copy: srw is [ch][tap] (i = ch*16 + tap)
            int tap = i & 15, ch = i >> 4;
            dst[SM_SRWT + tap*DD + ch] = (bf16)v;
        }
    }
}

// ---------------- weight transpose (512x512) ----------------
__global__ __launch_bounds__(256) void transpose512(
    const void* s0, const void* s1, const void* s2, const void* s3,
    bf16* __restrict__ d0, bf16* __restrict__ d1,
    bf16* __restrict__ d2, bf16* __restrict__ d3,
    const int* __restrict__ flag)
{
    __shared__ bf16 tile[32][33];
    bool f32 = (*flag != 0);
    int wsel = blockIdx.z;
    const void* src = wsel == 0 ? s0 : wsel == 1 ? s1 : wsel == 2 ? s2 : s3;
    bf16*       dst = wsel == 0 ? d0 : wsel == 1 ? d1 : wsel == 2 ? d2 : d3;
    float scl = (wsel == 0) ? 0.125f : 1.0f;
    int c0 = blockIdx.x * 32, n0 = blockIdx.y * 32;
    int tx = threadIdx.x, ty = threadIdx.y;
    #pragma unroll
    for (int i = 0; i < 4; i++) {
        size_t idx = (size_t)(c0 + ty + i*8) * 512 + n0 + tx;
        float v = f32 ? ((const float*)src)[idx] : (float)((const bf16*)src)[idx];
        tile[ty + i*8][tx] = (bf16)(v * scl);
    }
    __syncthreads();
    #pragma unroll
    for (int i = 0; i < 4; i++)
        dst[(size_t)(n0 + ty + i*8) * 512 + c0 + tx] = tile[tx][ty + i*8];
}

// ---------------- depthwise 4x4/s3 conv + LayerNorm (wave-per-output) ------------
__global__ __launch_bounds__(256) void sr_ln(
    const void* __restrict__ qraw, const bf16* __restrict__ qc,
    const bf16* __restrict__ sm, bf16* __restrict__ x,
    const int* __restrict__ flag)
{
    const bf16* q = (*flag) ? qc : (const bf16*)qraw;
    const int t = threadIdx.x;
    const int w = t >> 6, lane = t & 63;
    const int pos = blockIdx.x * 4 + w;        // b*256 + ok
    const int b = pos >> 8, ok = pos & 255;
    const int oh = ok >> 4, ow = ok & 15;
    const int c0 = lane * 8;

    float acc[8] = {};
    #pragma unroll
    for (int kh = 0; kh < 4; kh++) {
        int ih = oh*3 - 1 + kh;
        if (ih < 0) continue;
        #pragma unroll
        for (int kw = 0; kw < 4; kw++) {
            int iw = ow*3 - 1 + kw;
            if (iw < 0) continue;
            bf16x8 qv = *(const bf16x8*)(q + ((size_t)b*NQ + ih*48 + iw)*DD + c0);
            bf16x8 wv = *(const bf16x8*)(sm + SM_SRWT + (kh*4 + kw)*DD + c0);
            #pragma unroll
            for (int r = 0; r < 8; r++) acc[r] += (float)qv[r] * (float)wv[r];
        }
    }
    bf16x8 sb = *(const bf16x8*)(sm + SM_SRB + c0);
    #pragma unroll
    for (int r = 0; r < 8; r++) acc[r] += (float)sb[r];

    float s = 0.f, s2 = 0.f;
    #pragma unroll
    for (int r = 0; r < 8; r++) { s += acc[r]; s2 += acc[r]*acc[r]; }
    #pragma unroll
    for (int m = 1; m < 64; m <<= 1) { s += __shfl_xor(s, m); s2 += __shfl_xor(s2, m); }
    float mu  = s * (1.f/512.f);
    float var = s2 * (1.f/512.f) - mu*mu;
    float inv = rsqrtf(var + 1e-5f);

    bf16x8 gv = *(const bf16x8*)(sm + SM_LNG + c0);
    bf16x8 bv = *(const bf16x8*)(sm + SM_LNB + c0);
    bf16x8 outv;
    #pragma unroll
    for (int r = 0; r < 8; r++)
        outv[r] = (bf16)((acc[r] - mu) * inv * (float)gv[r] + (float)bv[r]);
    *(bf16x8*)(x + (size_t)pos * DD + c0) = outv;
}

// ---------------- generic BT-GEMM: C(M,512) = A(M,512) @ Bt(512,512)^T + bias ----------
// MODE 0: bf16 row-major store. MODE 1: V^T scatter store (b,h,dv,kk).
// MODE 2: output GEMM (plain WoT, dtype-branch store).
// MODE 4: A chosen by flag (raw vs converted queries).
template <int MODE>
__global__ __launch_bounds__(256) void gemm_bt(
    const bf16* __restrict__ A, const bf16* __restrict__ Bt,
    const bf16* __restrict__ bias, bf16* __restrict__ C,
    const int* __restrict__ of32, const bf16* __restrict__ A2)
{
    constexpr int K = 512;
    __shared__ bf16 Al[128 * 64];
    __shared__ bf16 Bl[128 * 64];
    const int m0 = blockIdx.x * 128, n0 = blockIdx.y * 128;
    const int t = threadIdx.x;
    const int lane = t & 63, w = t >> 6;
    const int wr = w >> 1, wc = w & 1;
    const int gg = lane >> 4, li = lane & 15;
    const int fsw = (li & 7) << 4;
    bool f32o = false;
    if (MODE == 2 || MODE == 4) f32o = (*of32 != 0);

    const bf16* Ab = A;
    if (MODE == 4) Ab = f32o ? A2 : A;

    f32x4 acc[4][4] = {};

    for (int k0 = 0; k0 < K; k0 += 64) {
        #pragma unroll
        for (int p = 0; p < 4; p++) {
            int off = p*4096 + t*16;
            int row = off >> 7;
            int col = ((((off >> 4) & 7) ^ (row & 7)) << 3);
            gload_lds16(Ab + (size_t)(m0 + row)*K + k0 + col, (char*)Al + off);
        }
        #pragma unroll
        for (int p = 0; p < 4; p++) {
            int off = p*4096 + t*16;
            int row = off >> 7;
            int col = ((((off >> 4) & 7) ^ (row & 7)) << 3);
            gload_lds16(Bt + (size_t)(n0 + row)*K + k0 + col, (char*)Bl + off);
        }
        __syncthreads();
        #pragma unroll
        for (int kk = 0; kk < 2; kk++) {
            bf16x8 af[4], bfr[4];
            #pragma unroll
            for (int i = 0; i < 4; i++) {
                af[i]  = *(const bf16x8*)((char*)Al + (wr*64 + i*16 + li)*128 + ((kk*64 + gg*16) ^ fsw));
                bfr[i] = *(const bf16x8*)((char*)Bl + (wc*64 + i*16 + li)*128 + ((kk*64 + gg*16) ^ fsw));
            }
            __builtin_amdgcn_s_setprio(1);
            #pragma unroll
            for (int i = 0; i < 4; i++)
                #pragma unroll
                for (int j = 0; j < 4; j++)
                    acc[i][j] = __builtin_amdgcn_mfma_f32_16x16x32_bf16(af[i], bfr[j], acc[i][j], 0, 0, 0);
            __builtin_amdgcn_s_setprio(0);
        }
        __syncthreads();
    }

    #pragma unroll
    for (int i = 0; i < 4; i++) {
        #pragma unroll
        for (int j = 0; j < 4; j++) {
            int rbase = m0 + wr*64 + i*16 + gg*4;
            int c     = n0 + wc*64 + j*16 + li;
            float bv = (float)bias[c];
            #pragma unroll
            for (int jj = 0; jj < 4; jj++) {
                float val = acc[i][j][jj] + bv;
                int r = rbase + jj;
                if (MODE == 1) {
                    int bb = r >> 8, kk2 = r & 255;
                    int hh = c >> 6, dv = c & 63;
                    C[(((size_t)(bb*8 + hh))*64 + dv)*256 + kk2] = (bf16)val;
                } else if (MODE == 2) {
                    if (f32o) ((float*)C)[(size_t)r * 512 + c] = val;
                    else      C[(size_t)r * 512 + c] = (bf16)val;
                } else {
                    C[(size_t)r * 512 + c] = (bf16)val;
                }
            }
        }
    }
}

// ---------------- S-GEMM: S[plane] = Q_i @ K_i^T  (M=2304,N=256,K=64) ----------------
__global__ __launch_bounds__(256) void gemm_s(
    const bf16* __restrict__ Qf, const bf16* __restrict__ Kt, bf16* __restrict__ S,
    int b0)
{
    __shared__ bf16 Al[128 * 64];
    __shared__ bf16 Bl[128 * 64];
    const int m0 = blockIdx.x * 128, n0 = blockIdx.y * 128;
    const int bo = blockIdx.z;
    const int b = b0 + (bo >> 3), ih = bo & 7;
    const int t = threadIdx.x;
    const int lane = t & 63, w = t >> 6;
    const int wr = w >> 1, wc = w & 1;
    const int gg = lane >> 4, li = lane & 15;
    const int fsw = (li & 7) << 4;

    #pragma unroll
    for (int p = 0; p < 4; p++) {
        int off = p*4096 + t*16;
        int row = off >> 7;
        int col = ((((off >> 4) & 7) ^ (row & 7)) << 3);
        gload_lds16(Qf + ((size_t)(b*NQ + m0 + row))*DD + ih*64 + col, (char*)Al + off);
    }
    #pragma unroll
    for (int p = 0; p < 4; p++) {
        int off = p*4096 + t*16;
        int row = off >> 7;
        int col = ((((off >> 4) & 7) ^ (row & 7)) << 3);
        gload_lds16(Kt + ((size_t)(b*NKV + n0 + row))*DD + ih*64 + col, (char*)Bl + off);
    }
    __syncthreads();

    f32x4 acc[4][4] = {};
    #pragma unroll
    for (int kk = 0; kk < 2; kk++) {
        bf16x8 af[4], bfr[4];
        #pragma unroll
        for (int i = 0; i < 4; i++) {
            af[i]  = *(const bf16x8*)((char*)Al + (wr*64 + i*16 + li)*128 + ((kk*64 + gg*16) ^ fsw));
            bfr[i] = *(const bf16x8*)((char*)Bl + (wc*64 + i*16 + li)*128 + ((kk*64 + gg*16) ^ fsw));
        }
        __builtin_amdgcn_s_setprio(1);
        #pragma unroll
        for (int i = 0; i < 4; i++)
            #pragma unroll
            for (int j = 0; j < 4; j++)
                acc[i][j] = __builtin_amdgcn_mfma_f32_16x16x32_bf16(af[i], bfr[j], acc[i][j], 0, 0, 0);
        __builtin_amdgcn_s_setprio(0);
    }

    bf16* Sb = S + (size_t)bo * NQ * NKV;
    #pragma unroll
    for (int i = 0; i < 4; i++) {
        #pragma unroll
        for (int j = 0; j < 4; j++) {
            int rbase = m0 + wr*64 + i*16 + gg*4;
            int c     = n0 + wc*64 + j*16 + li;
            #pragma unroll
            for (int jj = 0; jj < 4; jj++)
                Sb[(size_t)(rbase + jj) * NKV + c] = (bf16)acc[i][j][jj];
        }
    }
}

// ---------------- mix + softmax + dev + ssq (streaming, IN-PLACE on S) ----------------
// R14's exact verified structure; exp = raw v_exp (log2e pre-folded into twf).
// grid (144, CB); 256 thr = 4 waves; wave = 4 q-rows.
__global__ __launch_bounds__(256) void mix_softmax(
    bf16* __restrict__ S, const float* __restrict__ twf,
    float* __restrict__ ssq_g, int b0)
{
    const int t = threadIdx.x;
    const int lane = t & 63, w = t >> 6;
    const int bl = blockIdx.y;
    const int b  = b0 + bl;
    const int q0 = blockIdx.x * 16 + w * 4;
    __shared__ float rpar[4][8];

    float tw[8][8];
    #pragma unroll
    for (int o = 0; o < 8; o++)
        #pragma unroll
        for (int i = 0; i < 8; i++)
            tw[o][i] = twf[o*8 + i];     // uniform address -> scalar load

    float ssqL[8] = {};
    for (int qi = 0; qi < 4; qi++) {
        float s[8][4];
        #pragma unroll
        for (int i = 0; i < 8; i++) {
            bf16x4 v = *(const bf16x4*)(S + (((size_t)(bl*8 + i))*NQ + (q0 + qi))*NKV + lane*4);
            #pragma unroll
            for (int r = 0; r < 4; r++) s[i][r] = (float)v[r];
        }
        float e[8][4], inv[8];
        #pragma unroll
        for (int o = 0; o < 8; o++) {
            float sum = 0.f;
            #pragma unroll
            for (int r = 0; r < 4; r++) {
                float a = 0.f;
                #pragma unroll
                for (int i = 0; i < 8; i++) a += tw[o][i] * s[i][r];
                e[o][r] = __builtin_amdgcn_exp2f(a);   // tw carries log2(e)
                sum += e[o][r];
            }
            #pragma unroll
            for (int m = 1; m < 64; m <<= 1) sum += __shfl_xor(sum, m);
            inv[o] = 1.0f / sum;
        }
        #pragma unroll
        for (int o = 0; o < 8; o++) {
            bf16x4 dv;
            #pragma unroll
            for (int r = 0; r < 4; r++) {
                float d = e[o][r] * inv[o] - (1.0f/256.0f);
                ssqL[o] += d * d;
                dv[r] = (bf16)d;
            }
            *(bf16x4*)(S + (((size_t)(bl*8 + o))*NQ + (q0 + qi))*NKV + lane*4) = dv;
        }
    }
    #pragma unroll
    for (int o = 0; o < 8; o++) {
        float s = ssqL[o];
        #pragma unroll
        for (int m = 1; m < 64; m <<= 1) s += __shfl_xor(s, m);
        if (lane == 0) rpar[w][o] = s;
    }
    __syncthreads();
    if (t < 8) {
        float tot = rpar[0][t] + rpar[1][t] + rpar[2][t] + rpar[3][t];
        atomicAdd(&ssq_g[b*8 + t], tot);
    }
}

// ---------------- PV-GEMM: U = (Dev @ V) * rsqrt(var+eps), per (b,o) plane --------
// ssq_g[b*8+o] is complete before this launches (same-stream ordering).
__global__ __launch_bounds__(256) void gemm_pv(
    const bf16* __restrict__ Dev, const bf16* __restrict__ VT, bf16* __restrict__ U,
    const float* __restrict__ ssq_g, int b0)
{
    __shared__ bf16 Al[128 * 64];
    __shared__ bf16 Bl[64 * 64];
    const int m0 = blockIdx.x * 128;
    const int bo = blockIdx.y;
    const int b = b0 + (bo >> 3), o = bo & 7;
    const int t = threadIdx.x;
    const int lane = t & 63, w = t >> 6;
    const int wr = w >> 1, wc = w & 1;
    const int gg = lane >> 4, li = lane & 15;
    const int fsw = (li & 7) << 4;

    const bf16* Ab = Dev + (size_t)bo * NQ * NKV;
    const bf16* Bb = VT + ((size_t)(b*8 + o)) * 64 * NKV;
    const float sc = rsqrtf(ssq_g[b*8 + o] * (1.0f / ((float)NQ * (float)NKV)) + 1e-5f);

    f32x4 acc[4][2] = {};

    for (int k0 = 0; k0 < 256; k0 += 64) {
        #pragma unroll
        for (int p = 0; p < 4; p++) {
            int off = p*4096 + t*16;
            int row = off >> 7;
            int col = ((((off >> 4) & 7) ^ (row & 7)) << 3);
            gload_lds16(Ab + (size_t)(m0 + row)*NKV + k0 + col, (char*)Al + off);
        }
        #pragma unroll
        for (int p = 0; p < 2; p++) {
            int off = p*4096 + t*16;
            int row = off >> 7;
            int col = ((((off >> 4) & 7) ^ (row & 7)) << 3);
            gload_lds16(Bb + (size_t)row*NKV + k0 + col, (char*)Bl + off);
        }
        __syncthreads();
        #pragma unroll
        for (int kk = 0; kk < 2; kk++) {
            bf16x8 af[4], bfr[2];
            #pragma unroll
            for (int i = 0; i < 4; i++)
                af[i] = *(const bf16x8*)((char*)Al + (wr*64 + i*16 + li)*128 + ((kk*64 + gg*16) ^ fsw));
            #pragma unroll
            for (int j = 0; j < 2; j++)
                bfr[j] = *(const bf16x8*)((char*)Bl + (wc*32 + j*16 + li)*128 + ((kk*64 + gg*16) ^ fsw));
            __builtin_amdgcn_s_setprio(1);
            #pragma unroll
            for (int i = 0; i < 4; i++)
                #pragma unroll
                for (int j = 0; j < 2; j++)
                    acc[i][j] = __builtin_amdgcn_mfma_f32_16x16x32_bf16(af[i], bfr[j], acc[i][j], 0, 0, 0);
            __builtin_amdgcn_s_setprio(0);
        }
        __syncthreads();
    }

    #pragma unroll
    for (int i = 0; i < 4; i++) {
        #pragma unroll
        for (int j = 0; j < 2; j++) {
            int rbase = m0 + wr*64 + i*16 + gg*4;
            int c = wc*32 + j*16 + li;
            #pragma unroll
            for (int jj = 0; jj < 4; jj++)
                U[((size_t)b*NQ + rbase + jj)*DD + o*64 + c] = (bf16)(acc[i][j][jj] * sc);
        }
    }
}

// ======================================================================
extern "C" void kernel_launch(void* const* d_in, const int* in_sizes, int n_in,
                              void* d_out, int out_size, void* d_ws, size_t ws_size,
                              hipStream_t stream)
{
    const void* queries = d_in[0];
    const void* Wq = d_in[1];  const void* bq = d_in[2];
    const void* Wk = d_in[3];  const void* bk = d_in[4];
    const void* Wv = d_in[5];  const void* bv = d_in[6];
    const void* Wo = d_in[7];  const void* bo = d_in[8];
    const void* srw = d_in[9]; const void* srb = d_in[10];
    const void* lng = d_in[11]; const void* lnb = d_in[12];
    const void* tw  = d_in[13];
    // d_in[14] = tb: cancels in softmax; unused.

    char* ws = (char*)d_ws;
    bf16* WqT = (bf16*)(ws + OFF_WQT);
    bf16* WkT = (bf16*)(ws + OFF_WKT);
    bf16* WvT = (bf16*)(ws + OFF_WVT);
    bf16* WoT = (bf16*)(ws + OFF_WOT);
    bf16* xb  = (bf16*)(ws + OFF_X);
    bf16* Kt  = (bf16*)(ws + OFF_KT);
    bf16* VTb = (bf16*)(ws + OFF_VT);
    bf16* Qf  = (bf16*)(ws + OFF_QF);
    bf16* Ub  = (bf16*)(ws + OFF_U);
    float* ss = (float*)(ws + OFF_SS);
    bf16* sm  = (bf16*)(ws + OFF_SM);
    float* twf = (float*)(ws + OFF_TWF);
    int* flag = (int*)(ws + OFF_FLG);
    bf16* Sb  = (bf16*)(ws + OFF_S);       // S/Dev chunk buffer (in-place mix)
    bf16* Qc  = Ub;                        // converted queries (f32 path)

    // chunk size: largest CB that fits (R7 proved CB=16 fits this harness)
    int CB = 1;
    if      (OFF_S + 16*8*SPLANE <= ws_size) CB = 16;
    else if (OFF_S +  8*8*SPLANE <= ws_size) CB = 8;
    else if (OFF_S +  4*8*SPLANE <= ws_size) CB = 4;
    else if (OFF_S +  2*8*SPLANE <= ws_size) CB = 2;

    detect_dtype<<<dim3(1), dim3(64), 0, stream>>>((const uint32_t*)queries, flag);
    hipMemsetAsync(ss, 0, 128 * sizeof(float), stream);

    convert_q<<<dim3(9216), dim3(256), 0, stream>>>(queries, Qc, flag);
    convert_small<<<dim3(9), dim3(256), 0, stream>>>(bq, bk, bv, bo, srw, srb, lng, lnb, tw, sm, twf, flag);
    transpose512<<<dim3(16, 16, 4), dim3(32, 8), 0, stream>>>(Wq, Wk, Wv, Wo, WqT, WkT, WvT, WoT, flag);

    sr_ln<<<dim3(NB * NKV / 4), dim3(256), 0, stream>>>(queries, Qc, sm, xb, flag);
    gemm_bt<0><<<dim3(32, 4), dim3(256), 0, stream>>>(xb, WkT, sm + SM_BK, Kt, nullptr, nullptr);
    gemm_bt<1><<<dim3(32, 4), dim3(256), 0, stream>>>(xb, WvT, sm + SM_BV, VTb, nullptr, nullptr);
    gemm_bt<4><<<dim3(288, 4), dim3(256), 0, stream>>>((const bf16*)queries, WqT, sm + SM_BQ, Qf, flag, Qc);

    for (int b0 = 0; b0 < NB; b0 += CB) {
        gemm_s<<<dim3(18, 2, CB*8), dim3(256), 0, stream>>>(Qf, Kt, Sb, b0);
        mix_softmax<<<dim3(144, CB), dim3(256), 0, stream>>>(Sb, twf, ss, b0);
        gemm_pv<<<dim3(18, CB*8), dim3(256), 0, stream>>>(Sb, VTb, Ub, ss, b0);
    }

    gemm_bt<2><<<dim3(288, 4), dim3(256), 0, stream>>>(Ub, WoT, sm + SM_BO, (bf16*)d_out, flag, nullptr);
}